// Round 2
// baseline (2493.319 us; speedup 1.0000x reference)
//
#include <hip/hip_runtime.h>

#define B_ 8
#define H_ 96
#define W_ 96
#define L_ (H_*W_)          // 9216
#define M_ (B_*L_)          // 73728
#define DM 192
#define DI 384
#define DS 64
#define CD 448              // DI+DS
#define NH 6
#define HD 64
#define SCALE_ 0.125f
#define LSPLIT 6            // l-chunks for attention partials

typedef unsigned short bfu;

__device__ __forceinline__ float sigm(float x){ return 1.f/(1.f+__expf(-x)); }
__device__ __forceinline__ float b2f(bfu h){ return __uint_as_float(((unsigned)h)<<16); }
__device__ __forceinline__ bfu f2b(float f){
  unsigned x = __float_as_uint(f);
  return (bfu)((x + 0x7fffu + ((x>>16)&1u)) >> 16);
}
__device__ __forceinline__ float4 ld4(const float* p){ return *(const float4*)p; }
__device__ __forceinline__ float4 ld4(const bfu* p){
  ushort4 u = *(const ushort4*)p;
  return make_float4(b2f(u.x), b2f(u.y), b2f(u.z), b2f(u.w));
}
__device__ __forceinline__ void st4(float* p, float4 v){ *(float4*)p = v; }
__device__ __forceinline__ void st4(bfu* p, float4 v){
  ushort4 u; u.x=f2b(v.x); u.y=f2b(v.y); u.z=f2b(v.z); u.w=f2b(v.w);
  *(ushort4*)p = u;
}

// ---------------- generic 64x64 tiled GEMM, f32 accumulate ----------------
// C[m,n] = sum_k A[m,k]*B[k,n]   (BT=false)   or   A[m,k]*B[n,k]  (BT=true)
// col < splitN -> C0 else C1(col-splitN). batched via blockIdx.z.
template<bool BT, bool BIAS, class TA, class TB, class TC0, class TC1>
__global__ __launch_bounds__(256) void gemm64(
    const TA* __restrict__ A, const TB* __restrict__ Bm,
    const float* __restrict__ bias,
    TC0* __restrict__ C0, TC1* __restrict__ C1,
    int K, int lda, int ldb, int splitN, int ldc0, int ldc1,
    long sA, long sB, long sC)
{
  __shared__ float Ast[32][68];
  __shared__ float Bs[32][68];
  const int tid = threadIdx.x;
  const int tx = tid & 15, ty = tid >> 4;
  const int n0 = blockIdx.x * 64, m0 = blockIdx.y * 64;
  const int zb = blockIdx.z;
  A  += (long)zb * sA;
  Bm += (long)zb * sB;
  float acc[4][4] = {};
  for (int k0 = 0; k0 < K; k0 += 32) {
    for (int v = tid; v < 512; v += 256) {
      int r = v >> 3, kq = (v & 7) << 2;
      float4 f = ld4(A + (long)(m0 + r) * lda + (k0 + kq));
      Ast[kq+0][r] = f.x; Ast[kq+1][r] = f.y; Ast[kq+2][r] = f.z; Ast[kq+3][r] = f.w;
    }
    if (!BT) {
      for (int v = tid; v < 512; v += 256) {
        int r = v >> 4, nq = (v & 15) << 2;
        float4 f = ld4(Bm + (long)(k0 + r) * ldb + (n0 + nq));
        *(float4*)&Bs[r][nq] = f;
      }
    } else {
      for (int v = tid; v < 512; v += 256) {
        int n = v >> 3, kq = (v & 7) << 2;
        float4 f = ld4(Bm + (long)(n0 + n) * ldb + (k0 + kq));
        Bs[kq+0][n] = f.x; Bs[kq+1][n] = f.y; Bs[kq+2][n] = f.z; Bs[kq+3][n] = f.w;
      }
    }
    __syncthreads();
    #pragma unroll
    for (int kk = 0; kk < 32; ++kk) {
      float4 av = *(const float4*)&Ast[kk][ty*4];
      float4 bv = *(const float4*)&Bs[kk][tx*4];
      acc[0][0] += av.x*bv.x; acc[0][1] += av.x*bv.y; acc[0][2] += av.x*bv.z; acc[0][3] += av.x*bv.w;
      acc[1][0] += av.y*bv.x; acc[1][1] += av.y*bv.y; acc[1][2] += av.y*bv.z; acc[1][3] += av.y*bv.w;
      acc[2][0] += av.z*bv.x; acc[2][1] += av.z*bv.y; acc[2][2] += av.z*bv.z; acc[2][3] += av.z*bv.w;
      acc[3][0] += av.w*bv.x; acc[3][1] += av.w*bv.y; acc[3][2] += av.w*bv.z; acc[3][3] += av.w*bv.w;
    }
    __syncthreads();
  }
  const int colg = n0 + tx*4;
  #pragma unroll
  for (int i = 0; i < 4; ++i) {
    int row = m0 + ty*4 + i;
    float4 o = make_float4(acc[i][0], acc[i][1], acc[i][2], acc[i][3]);
    if (BIAS) { o.x += bias[colg]; o.y += bias[colg+1]; o.z += bias[colg+2]; o.w += bias[colg+3]; }
    if (colg < splitN)
      st4(C0 + (long)zb*sC + (long)row*ldc0 + colg, o);
    else
      st4(C1 + (long)row*ldc1 + (colg - splitN), o);
  }
}

// ---------------- depthwise 3x3 + bias + silu (NHWC bf16, C=448) ----------------
__global__ __launch_bounds__(256) void conv3x3_silu(
    const bfu* __restrict__ xB, const float* __restrict__ cw,
    const float* __restrict__ cb, bfu* __restrict__ out)
{
  int idx = blockIdx.x * 256 + threadIdx.x;   // M_*112
  if (idx >= M_*112) return;
  int p = idx / 112, cq = idx % 112, c0 = cq << 2;
  int l = p % L_, h = l / W_, w = l % W_;
  float4 bq = ld4(cb + c0);
  float a0 = bq.x, a1 = bq.y, a2 = bq.z, a3 = bq.w;
  float wgt[4][9];
  #pragma unroll
  for (int i = 0; i < 4; ++i)
    #pragma unroll
    for (int t = 0; t < 9; ++t) wgt[i][t] = cw[(c0+i)*9 + t];
  #pragma unroll
  for (int dh = -1; dh <= 1; ++dh) {
    int h2 = h + dh; if ((unsigned)h2 >= (unsigned)H_) continue;
    #pragma unroll
    for (int dw = -1; dw <= 1; ++dw) {
      int w2 = w + dw; if ((unsigned)w2 >= (unsigned)W_) continue;
      float4 v = ld4(xB + ((long)p + dh*W_ + dw) * CD + c0);
      int t = (dh+1)*3 + (dw+1);
      a0 += v.x * wgt[0][t]; a1 += v.y * wgt[1][t];
      a2 += v.z * wgt[2][t]; a3 += v.w * wgt[3][t];
    }
  }
  float4 o;
  o.x = a0 * sigm(a0); o.y = a1 * sigm(a1); o.z = a2 * sigm(a2); o.w = a3 * sigm(a3);
  st4(out + (long)p * CD + c0, o);
}

// ---------------- K_soft: sigmoid + normalize over 64 states ----------------
__global__ __launch_bounds__(256) void ksoft_kernel(
    const bfu* __restrict__ xB2, bfu* __restrict__ Ksoft)
{
  int p = blockIdx.x * 4 + (threadIdx.x >> 6);
  int lane = threadIdx.x & 63;
  float v = b2f(xB2[(long)p * CD + DI + lane]);
  float k = sigm(v);
  float s = k;
  #pragma unroll
  for (int o = 32; o; o >>= 1) s += __shfl_xor(s, o);
  Ksoft[((long)p << 6) + lane] = f2b(k / (s + 1e-6f));
}

// ---------------- depthwise 5x5 + bias (in: bf16 ld CD; out: bf16 ld DI) ----------------
__global__ __launch_bounds__(256) void conv5x5(
    const bfu* __restrict__ xin, const float* __restrict__ cw,
    const float* __restrict__ cb, bfu* __restrict__ out)
{
  int idx = blockIdx.x * 256 + threadIdx.x;   // M_*96
  if (idx >= M_*96) return;
  int p = idx / 96, c0 = (idx % 96) << 2;
  int l = p % L_, h = l / W_, w = l % W_;
  float4 bq = ld4(cb + c0);
  float a0 = bq.x, a1 = bq.y, a2 = bq.z, a3 = bq.w;
  #pragma unroll
  for (int dh = -2; dh <= 2; ++dh) {
    int h2 = h + dh; if ((unsigned)h2 >= (unsigned)H_) continue;
    #pragma unroll
    for (int dw = -2; dw <= 2; ++dw) {
      int w2 = w + dw; if ((unsigned)w2 >= (unsigned)W_) continue;
      float4 v = ld4(xin + ((long)p + dh*W_ + dw) * CD + c0);
      int t = (dh+2)*5 + (dw+2);
      a0 += v.x * cw[(c0+0)*25 + t]; a1 += v.y * cw[(c0+1)*25 + t];
      a2 += v.z * cw[(c0+2)*25 + t]; a3 += v.w * cw[(c0+3)*25 + t];
    }
  }
  st4(out + (long)p * DI + c0, make_float4(a0,a1,a2,a3));
}

// ---------------- proto partials over l-chunk: part[bh][ch][s][d] ----------------
__global__ __launch_bounds__(256) void proto_part(
    const bfu* __restrict__ Ksf, const bfu* __restrict__ Vs, float* __restrict__ part)
{
  const int ch = blockIdx.x, bh = blockIdx.y;
  const int b = bh / NH, hh = bh % NH;
  __shared__ float Ks[32][68], Vt[32][68];
  const int tid = threadIdx.x, tx = tid & 15, ty = tid >> 4;
  float acc[4][4] = {};
  const int lbeg = ch * (L_/LSPLIT);
  for (int l0 = lbeg; l0 < lbeg + L_/LSPLIT; l0 += 32) {
    for (int v = tid; v < 512; v += 256) {
      int r = v >> 4, q = (v & 15) << 2;
      long lrow = (long)b * L_ + l0 + r;
      *(float4*)&Ks[r][q] = ld4(Ksf + (lrow << 6) + q);
      *(float4*)&Vt[r][q] = ld4(Vs + lrow * DI + hh*HD + q);
    }
    __syncthreads();
    #pragma unroll
    for (int kk = 0; kk < 32; ++kk) {
      float4 av = *(const float4*)&Ks[kk][ty*4];
      float4 bv = *(const float4*)&Vt[kk][tx*4];
      acc[0][0] += av.x*bv.x; acc[0][1] += av.x*bv.y; acc[0][2] += av.x*bv.z; acc[0][3] += av.x*bv.w;
      acc[1][0] += av.y*bv.x; acc[1][1] += av.y*bv.y; acc[1][2] += av.y*bv.z; acc[1][3] += av.y*bv.w;
      acc[2][0] += av.z*bv.x; acc[2][1] += av.z*bv.y; acc[2][2] += av.z*bv.z; acc[2][3] += av.z*bv.w;
      acc[3][0] += av.w*bv.x; acc[3][1] += av.w*bv.y; acc[3][2] += av.w*bv.z; acc[3][3] += av.w*bv.w;
    }
    __syncthreads();
  }
  float* dst = part + ((long)bh*LSPLIT + ch) * 4096;
  #pragma unroll
  for (int i = 0; i < 4; ++i)
    *(float4*)(dst + (ty*4+i)*64 + tx*4) = make_float4(acc[i][0],acc[i][1],acc[i][2],acc[i][3]);
}

// ---------------- reduce LSPLIT proto chunks ----------------
__global__ __launch_bounds__(256) void reduce_proto(
    const float* __restrict__ part, float* __restrict__ proto)
{
  int idx = blockIdx.x * 256 + threadIdx.x;   // 48*4096
  int bh = idx >> 12, sd = idx & 4095;
  const float* p = part + ((long)bh*LSPLIT)*4096 + sd;
  float s = 0.f;
  #pragma unroll
  for (int c = 0; c < LSPLIT; ++c) s += p[c*4096];
  proto[idx] = s;
}

// ---------------- flash PV: streaming exp(S)-weighted accumulation ----------------
// max-free softmax: scores are O(0.1) by construction, exp can't overflow.
__global__ __launch_bounds__(256) void flashpv(
    const float* __restrict__ proto, const bfu* __restrict__ Vs,
    float* __restrict__ pacc_part, float* __restrict__ dsum_part)
{
  const int ch = blockIdx.x, bh = blockIdx.y;
  const int b = bh / NH, hh = bh % NH;
  __shared__ float Pt[64][68];     // proto[s][d]
  __shared__ float Vt[32][68];     // V chunk [l][d]
  __shared__ float Ptl[32][68];    // P tile [l][s]
  const int tid = threadIdx.x, tx = tid & 15, ty = tid >> 4;
  for (int v = tid; v < 1024; v += 256) {
    int r = v >> 4, q = (v & 15) << 2;
    *(float4*)&Pt[r][q] = *(const float4*)(proto + ((long)bh << 12) + (r << 6) + q);
  }
  float pacc[4][4] = {};
  float dsum[4] = {};
  const int lbeg = ch * (L_/LSPLIT);
  for (int l0 = lbeg; l0 < lbeg + L_/LSPLIT; l0 += 32) {
    __syncthreads();     // protect Vt/Ptl from prev-iter readers (also fences Pt load, iter 0)
    for (int v = tid; v < 512; v += 256) {
      int r = v >> 4, q = (v & 15) << 2;
      *(float4*)&Vt[r][q] = ld4(Vs + ((long)b * L_ + l0 + r) * DI + hh*HD + q);
    }
    __syncthreads();
    // S = proto @ V^T for l = tx, tx+16 ; s = ty*4+i ; P = exp(S*scale)
    #pragma unroll
    for (int h2 = 0; h2 < 2; ++h2) {
      int lc = tx + (h2 << 4);
      float s0=0.f, s1=0.f, s2=0.f, s3=0.f;
      #pragma unroll
      for (int d = 0; d < 64; ++d) {
        float vd = Vt[lc][d];
        s0 += Pt[ty*4+0][d]*vd; s1 += Pt[ty*4+1][d]*vd;
        s2 += Pt[ty*4+2][d]*vd; s3 += Pt[ty*4+3][d]*vd;
      }
      Ptl[lc][ty*4+0] = __expf(s0*SCALE_);
      Ptl[lc][ty*4+1] = __expf(s1*SCALE_);
      Ptl[lc][ty*4+2] = __expf(s2*SCALE_);
      Ptl[lc][ty*4+3] = __expf(s3*SCALE_);
    }
    __syncthreads();
    #pragma unroll
    for (int kk = 0; kk < 32; ++kk) {
      float4 av = *(const float4*)&Ptl[kk][ty*4];
      float4 bv = *(const float4*)&Vt[kk][tx*4];
      pacc[0][0] += av.x*bv.x; pacc[0][1] += av.x*bv.y; pacc[0][2] += av.x*bv.z; pacc[0][3] += av.x*bv.w;
      pacc[1][0] += av.y*bv.x; pacc[1][1] += av.y*bv.y; pacc[1][2] += av.y*bv.z; pacc[1][3] += av.y*bv.w;
      pacc[2][0] += av.z*bv.x; pacc[2][1] += av.z*bv.y; pacc[2][2] += av.z*bv.z; pacc[2][3] += av.z*bv.w;
      pacc[3][0] += av.w*bv.x; pacc[3][1] += av.w*bv.y; pacc[3][2] += av.w*bv.z; pacc[3][3] += av.w*bv.w;
      dsum[0] += av.x; dsum[1] += av.y; dsum[2] += av.z; dsum[3] += av.w;
    }
  }
  float* dst = pacc_part + ((long)bh*LSPLIT + ch) * 4096;
  #pragma unroll
  for (int i = 0; i < 4; ++i)
    *(float4*)(dst + (ty*4+i)*64 + tx*4) = make_float4(pacc[i][0],pacc[i][1],pacc[i][2],pacc[i][3]);
  if (tx == 0) {
    #pragma unroll
    for (int i = 0; i < 4; ++i)
      dsum_part[((long)bh*LSPLIT + ch)*64 + ty*4 + i] = dsum[i];
  }
}

// ---------------- reduce flash partials -> R2[b][s][hh*64+d] (f32) ----------------
__global__ __launch_bounds__(256) void reduce_R2(
    const float* __restrict__ pacc_part, const float* __restrict__ dsum_part,
    float* __restrict__ R2)
{
  int idx = blockIdx.x * 256 + threadIdx.x;   // 48*4096
  int bh = idx >> 12, s = (idx >> 6) & 63, d = idx & 63;
  int b = bh / NH, hh = bh % NH;
  float pa = 0.f, ds = 0.f;
  #pragma unroll
  for (int c = 0; c < LSPLIT; ++c) {
    pa += pacc_part[((long)bh*LSPLIT + c)*4096 + (s<<6) + d];
    ds += dsum_part[((long)bh*LSPLIT + c)*64 + s];
  }
  R2[((long)b*64 + s)*DI + hh*HD + d] = pa / ds;
}

// ---------------- fused: y = fine + V*D ; LayerNorm ; * z ----------------
__global__ __launch_bounds__(128) void ln_kernel(
    const bfu* __restrict__ fine, const bfu* __restrict__ xB2,
    const bfu* __restrict__ z, const float* __restrict__ Dv,
    const float* __restrict__ ln_g, const float* __restrict__ ln_b,
    bfu* __restrict__ yn)
{
  const int p = blockIdx.x;
  const int tid = threadIdx.x;
  __shared__ float sh[2], sh2[2];
  float y[3]; float s = 0.f, ss = 0.f;
  #pragma unroll
  for (int k = 0; k < 3; ++k) {
    int c = tid + (k << 7);
    float f = b2f(fine[(long)p*DI + c]) + b2f(xB2[(long)p*CD + c]) * Dv[c >> 6];
    y[k] = f; s += f; ss += f*f;
  }
  #pragma unroll
  for (int o = 32; o; o >>= 1) { s += __shfl_xor(s, o); ss += __shfl_xor(ss, o); }
  if ((tid & 63) == 0) { sh[tid >> 6] = s; sh2[tid >> 6] = ss; }
  __syncthreads();
  s = sh[0] + sh[1]; ss = sh2[0] + sh2[1];
  float mu = s * (1.f/384.f);
  float var = ss * (1.f/384.f) - mu*mu;
  float rs = rsqrtf(var + 1e-5f);
  #pragma unroll
  for (int k = 0; k < 3; ++k) {
    int c = tid + (k << 7);
    float o2 = (y[k] - mu) * rs * ln_g[c] + ln_b[c];
    yn[(long)p*DI + c] = f2b(o2 * b2f(z[(long)p*DI + c]));
  }
}

extern "C" void kernel_launch(void* const* d_in, const int* in_sizes, int n_in,
                              void* d_out, int out_size, void* d_ws, size_t ws_size,
                              hipStream_t stream) {
  const float* u      = (const float*)d_in[0];
  const float* W_in   = (const float*)d_in[1];
  const float* conv_w = (const float*)d_in[2];
  const float* conv_b = (const float*)d_in[3];
  const float* dw_w   = (const float*)d_in[4];
  const float* dw_b   = (const float*)d_in[5];
  const float* pw_w   = (const float*)d_in[6];
  const float* pw_b   = (const float*)d_in[7];
  const float* Dv     = (const float*)d_in[8];
  const float* ln_g   = (const float*)d_in[9];
  const float* ln_b   = (const float*)d_in[10];
  const float* W_out  = (const float*)d_in[11];
  float* out = (float*)d_out;

  // z_bf lives in d_out: M_*384*2 bytes == out_size*4 bytes exactly.
  bfu* z_bf = (bfu*)d_out;

  char* ws = (char*)d_ws;
  size_t off = 0;
  bfu* xB_bf  = (bfu*)(ws + off); off += (size_t)M_*CD*2;   // gemm1 out -> later fine_bf
  bfu* xB2_bf = (bfu*)(ws + off); off += (size_t)M_*CD*2;   // conv3 out (x | B'), live to LN
  bfu* xloc_bf= (bfu*)(ws + off); off += (size_t)M_*DI*2;   // conv5 out -> later yn_bf
  bfu* Vs_bf  = (bfu*)(ws + off); off += (size_t)M_*DI*2;
  bfu* Ksf_bf = (bfu*)(ws + off); off += (size_t)M_*DS*2;
  float* part  = (float*)(ws + off); off += (size_t)48*LSPLIT*4096*4;
  float* dsum  = (float*)(ws + off); off += (size_t)48*LSPLIT*64*4;
  float* proto = (float*)(ws + off); off += (size_t)48*4096*4;
  float* R2    = (float*)(ws + off); off += (size_t)8*64*DI*4;
  // total ~261 MB

  bfu* fine_bf = xB_bf;    // xB dead after conv3x3
  bfu* yn_bf   = xloc_bf;  // xloc dead after pointwise GEMM

  // 1) zxB = u @ W_in  (split: z_bf | xB_bf)
  gemm64<false,false,float,float,bfu,bfu><<<dim3(13,1152,1), 256, 0, stream>>>(
      u, W_in, nullptr, z_bf, xB_bf, 192, 192, 832, 384, 384, 448, 0, 0, 0);
  // 2) depthwise 3x3 + silu
  conv3x3_silu<<<(M_*112)/256, 256, 0, stream>>>(xB_bf, conv_w, conv_b, xB2_bf);
  // 2b) K_soft
  ksoft_kernel<<<M_/4, 256, 0, stream>>>(xB2_bf, Ksf_bf);
  // 3) depthwise 5x5
  conv5x5<<<(M_*96)/256, 256, 0, stream>>>(xB2_bf, dw_w, dw_b, xloc_bf);
  // 4) pointwise: Vs = xloc @ pw_w^T + pw_b
  gemm64<true,true,bfu,float,bfu,bfu><<<dim3(6,1152,1), 256, 0, stream>>>(
      xloc_bf, pw_w, pw_b, Vs_bf, (bfu*)nullptr, 384, 384, 384, 1<<30, 384, 0, 0, 0, 0);
  // 5) proto = Ksoft^T @ Vs (l-split partials + reduce)
  proto_part<<<dim3(LSPLIT,48), 256, 0, stream>>>(Ksf_bf, Vs_bf, part);
  reduce_proto<<<768, 256, 0, stream>>>(part, proto);
  // 6) flash attention (max-free streaming softmax), partials + reduce -> R2
  flashpv<<<dim3(LSPLIT,48), 256, 0, stream>>>(proto, Vs_bf, part, dsum);
  reduce_R2<<<768, 256, 0, stream>>>(part, dsum, R2);
  // 7) fine = Ksoft @ R2  (batched over b)
  gemm64<false,false,bfu,float,bfu,bfu><<<dim3(6,144,8), 256, 0, stream>>>(
      Ksf_bf, R2, nullptr, fine_bf, (bfu*)nullptr, 64, 64, 384, 1<<30, 384, 0,
      (long)L_*64, (long)64*DI, (long)L_*DI);
  // 8) y = fine + V*D ; LN ; *z
  ln_kernel<<<M_, 128, 0, stream>>>(fine_bf, xB2_bf, z_bf, Dv, ln_g, ln_b, yn_bf);
  // 9) out = yn @ W_out
  gemm64<false,false,bfu,float,float,float><<<dim3(3,1152,1), 256, 0, stream>>>(
      yn_bf, W_out, nullptr, out, (float*)nullptr, 384, 384, 192, 1<<30, 192, 0, 0, 0, 0);
}

// Round 3
// 935.580 us; speedup vs baseline: 2.6650x; 2.6650x over previous
//
#include <hip/hip_runtime.h>

#define B_ 8
#define H_ 96
#define W_ 96
#define L_ (H_*W_)          // 9216
#define M_ (B_*L_)          // 73728
#define DM 192
#define DI 384
#define DS 64
#define CD 448              // DI+DS
#define NH 6
#define HD 64
#define SCALE_ 0.125f
#define LSPLIT 6

typedef unsigned short bfu;
typedef __attribute__((ext_vector_type(8))) short bf16x8;
typedef __attribute__((ext_vector_type(4))) float f32x4;

__device__ __forceinline__ float sigm(float x){ return 1.f/(1.f+__expf(-x)); }
__device__ __forceinline__ float b2f(bfu h){ return __uint_as_float(((unsigned)h)<<16); }
__device__ __forceinline__ bfu f2b(float f){
  unsigned x = __float_as_uint(f);
  return (bfu)((x + 0x7fffu + ((x>>16)&1u)) >> 16);
}
__device__ __forceinline__ float4 ld4(const float* p){ return *(const float4*)p; }
__device__ __forceinline__ float4 ld4(const bfu* p){
  ushort4 u = *(const ushort4*)p;
  return make_float4(b2f(u.x), b2f(u.y), b2f(u.z), b2f(u.w));
}
__device__ __forceinline__ void st4(bfu* p, float4 v){
  ushort4 u; u.x=f2b(v.x); u.y=f2b(v.y); u.z=f2b(v.z); u.w=f2b(v.w);
  *(ushort4*)p = u;
}
// stage 8 elements (16B of bf16) into LDS
__device__ __forceinline__ void stage8(const bfu* src, bfu* dst){
  *(uint4*)dst = *(const uint4*)src;
}
__device__ __forceinline__ void stage8(const float* src, bfu* dst){
  float4 f0 = *(const float4*)src, f1 = *(const float4*)(src+4);
  ushort4 a; a.x=f2b(f0.x); a.y=f2b(f0.y); a.z=f2b(f0.z); a.w=f2b(f0.w);
  ushort4 b; b.x=f2b(f1.x); b.y=f2b(f1.y); b.z=f2b(f1.z); b.w=f2b(f1.w);
  *(ushort4*)dst = a; *(ushort4*)(dst+4) = b;
}
__device__ __forceinline__ void stel(float* p, float v){ *p = v; }
__device__ __forceinline__ void stel(bfu* p, float v){ *p = f2b(v); }

// ================= MFMA GEMM: C[m,n] = sum_k A[m,k]*Bw[n,k] (+bias) =================
// A: TA [M][lda] (lda==K), Bw: bf16 [N][K] pre-transposed. BM=128 BN=64 BK=64.
// col<splitN -> C0 (ldc0) else C1 (col-splitN, ldc1). batch via blockIdx.z.
template<bool BIAS, class TA, class TC0, class TC1>
__global__ __launch_bounds__(256) void gemm_mfma(
    const TA* __restrict__ A, const bfu* __restrict__ Bw,
    const float* __restrict__ bias,
    TC0* __restrict__ C0, TC1* __restrict__ C1,
    int K, int splitN, int ldc0, int ldc1,
    long sA, long sB, long sC)
{
  __shared__ bfu As[128][72];
  __shared__ bfu Bs[64][72];
  const int tid = threadIdx.x;
  const int n0 = blockIdx.x*64, m0 = blockIdx.y*128, zb = blockIdx.z;
  A  += (long)zb*sA;
  Bw += (long)zb*sB;
  const int wave = tid>>6, lane = tid&63;
  const int wr = wave>>1, wc = wave&1;
  const int lr = lane&15, lk = lane>>4;
  f32x4 acc[4][2];
  #pragma unroll
  for (int mr=0;mr<4;++mr)
    #pragma unroll
    for (int nr=0;nr<2;++nr){ acc[mr][nr][0]=0.f; acc[mr][nr][1]=0.f; acc[mr][nr][2]=0.f; acc[mr][nr][3]=0.f; }
  for (int k0 = 0; k0 < K; k0 += 64) {
    #pragma unroll
    for (int i = 0; i < 4; ++i) {
      int seg = i*256 + tid;          // 1024 segs of 8 elems
      int r = seg>>3, sg = seg&7;
      stage8(A + (long)(m0+r)*K + k0 + sg*8, &As[r][sg*8]);
    }
    #pragma unroll
    for (int i = 0; i < 2; ++i) {
      int seg = i*256 + tid;          // 512 segs
      int r = seg>>3, sg = seg&7;
      stage8(Bw + (long)(n0+r)*K + k0 + sg*8, &Bs[r][sg*8]);
    }
    __syncthreads();
    #pragma unroll
    for (int ks = 0; ks < 2; ++ks) {
      bf16x8 af[4], bfr[2];
      #pragma unroll
      for (int mr=0; mr<4; ++mr) af[mr]  = *(const bf16x8*)&As[wr*64+mr*16+lr][ks*32+lk*8];
      #pragma unroll
      for (int nr=0; nr<2; ++nr) bfr[nr] = *(const bf16x8*)&Bs[wc*32+nr*16+lr][ks*32+lk*8];
      #pragma unroll
      for (int mr=0; mr<4; ++mr)
        #pragma unroll
        for (int nr=0; nr<2; ++nr)
          acc[mr][nr] = __builtin_amdgcn_mfma_f32_16x16x32_bf16(af[mr], bfr[nr], acc[mr][nr], 0,0,0);
    }
    __syncthreads();
  }
  #pragma unroll
  for (int mr=0; mr<4; ++mr) {
    #pragma unroll
    for (int nr=0; nr<2; ++nr) {
      const int col = n0 + wc*32 + nr*16 + lr;
      const float badd = BIAS ? bias[col] : 0.f;
      #pragma unroll
      for (int i=0;i<4;++i) {
        const int row = m0 + wr*64 + mr*16 + lk*4 + i;
        const float v = acc[mr][nr][i] + badd;
        if (col < splitN) stel(C0 + (long)zb*sC + (long)row*ldc0 + col, v);
        else              stel(C1 + (long)row*ldc1 + (col - splitN), v);
      }
    }
  }
}

// ================= weight prep: transpose+convert to [N][K] bf16 =================
__global__ __launch_bounds__(256) void prep_w(
    const float* __restrict__ W_in, const float* __restrict__ pw_w,
    const float* __restrict__ W_out,
    bfu* __restrict__ Wt_in, bfu* __restrict__ pw_bf, bfu* __restrict__ Wt_out)
{
  int i = blockIdx.x*256 + threadIdx.x;
  const int n1 = 832*192, n2 = n1 + 384*384, n3 = n2 + 192*384;
  if (i < n1)      { int n=i/192, k=i%192; Wt_in[i]  = f2b(W_in[k*832+n]); }
  else if (i < n2) { int j=i-n1;           pw_bf[j]  = f2b(pw_w[j]); }
  else if (i < n3) { int j=i-n2; int n=j/384, k=j%384; Wt_out[j] = f2b(W_out[k*192+n]); }
}

// ================= depthwise 3x3 + silu, LDS halo tile (16x16 px, 8 ch) =================
__global__ __launch_bounds__(256) void conv3x3_t(
    const bfu* __restrict__ xB, const float* __restrict__ cw,
    const float* __restrict__ cb, bfu* __restrict__ out)
{
  const int tile = blockIdx.x, c0 = blockIdx.y*8, b = blockIdx.z;
  const int h0 = (tile/6)*16, w0 = (tile%6)*16;
  __shared__ alignas(16) bfu tl[18][18][8];
  __shared__ float wl[8][9];
  const int tid = threadIdx.x;
  if (tid < 72) wl[tid/9][tid%9] = cw[(c0 + tid/9)*9 + tid%9];
  for (int i = tid; i < 324; i += 256) {
    int y = i/18, x = i%18;
    int gh = h0+y-1, gw = w0+x-1;
    uint4 v = make_uint4(0,0,0,0);
    if ((unsigned)gh < 96u && (unsigned)gw < 96u)
      v = *(const uint4*)(xB + ((long)(b*L_ + gh*96+gw))*CD + c0);
    *(uint4*)&tl[y][x][0] = v;
  }
  __syncthreads();
  const int px = tid & 15, py = tid >> 4;
  float a[8];
  #pragma unroll
  for (int j=0;j<8;++j) a[j] = cb[c0+j];
  #pragma unroll
  for (int dh=0; dh<3; ++dh)
    #pragma unroll
    for (int dw=0; dw<3; ++dw) {
      uint4 r = *(const uint4*)&tl[py+dh][px+dw][0];
      int t = dh*3+dw;
      a[0] += __uint_as_float(r.x<<16)        * wl[0][t];
      a[1] += __uint_as_float(r.x&0xffff0000u)* wl[1][t];
      a[2] += __uint_as_float(r.y<<16)        * wl[2][t];
      a[3] += __uint_as_float(r.y&0xffff0000u)* wl[3][t];
      a[4] += __uint_as_float(r.z<<16)        * wl[4][t];
      a[5] += __uint_as_float(r.z&0xffff0000u)* wl[5][t];
      a[6] += __uint_as_float(r.w<<16)        * wl[6][t];
      a[7] += __uint_as_float(r.w&0xffff0000u)* wl[7][t];
    }
  #pragma unroll
  for (int j=0;j<8;++j) a[j] = a[j]*sigm(a[j]);
  uint4 o;
  o.x = (unsigned)f2b(a[0]) | ((unsigned)f2b(a[1])<<16);
  o.y = (unsigned)f2b(a[2]) | ((unsigned)f2b(a[3])<<16);
  o.z = (unsigned)f2b(a[4]) | ((unsigned)f2b(a[5])<<16);
  o.w = (unsigned)f2b(a[6]) | ((unsigned)f2b(a[7])<<16);
  *(uint4*)(out + ((long)(b*L_ + (h0+py)*96 + (w0+px)))*CD + c0) = o;
}

// ================= depthwise 5x5, LDS halo tile (16x16 px, 8 ch) =================
__global__ __launch_bounds__(256) void conv5x5_t(
    const bfu* __restrict__ xin, const float* __restrict__ cw,
    const float* __restrict__ cb, bfu* __restrict__ out)
{
  const int tile = blockIdx.x, c0 = blockIdx.y*8, b = blockIdx.z;
  const int h0 = (tile/6)*16, w0 = (tile%6)*16;
  __shared__ alignas(16) bfu tl[20][20][8];
  __shared__ float wl[8][25];
  const int tid = threadIdx.x;
  if (tid < 200) wl[tid/25][tid%25] = cw[(c0 + tid/25)*25 + tid%25];
  for (int i = tid; i < 400; i += 256) {
    int y = i/20, x = i%20;
    int gh = h0+y-2, gw = w0+x-2;
    uint4 v = make_uint4(0,0,0,0);
    if ((unsigned)gh < 96u && (unsigned)gw < 96u)
      v = *(const uint4*)(xin + ((long)(b*L_ + gh*96+gw))*CD + c0);
    *(uint4*)&tl[y][x][0] = v;
  }
  __syncthreads();
  const int px = tid & 15, py = tid >> 4;
  float a[8];
  #pragma unroll
  for (int j=0;j<8;++j) a[j] = cb[c0+j];
  #pragma unroll
  for (int dh=0; dh<5; ++dh)
    #pragma unroll
    for (int dw=0; dw<5; ++dw) {
      uint4 r = *(const uint4*)&tl[py+dh][px+dw][0];
      int t = dh*5+dw;
      a[0] += __uint_as_float(r.x<<16)        * wl[0][t];
      a[1] += __uint_as_float(r.x&0xffff0000u)* wl[1][t];
      a[2] += __uint_as_float(r.y<<16)        * wl[2][t];
      a[3] += __uint_as_float(r.y&0xffff0000u)* wl[3][t];
      a[4] += __uint_as_float(r.z<<16)        * wl[4][t];
      a[5] += __uint_as_float(r.z&0xffff0000u)* wl[5][t];
      a[6] += __uint_as_float(r.w<<16)        * wl[6][t];
      a[7] += __uint_as_float(r.w&0xffff0000u)* wl[7][t];
    }
  uint4 o;
  o.x = (unsigned)f2b(a[0]) | ((unsigned)f2b(a[1])<<16);
  o.y = (unsigned)f2b(a[2]) | ((unsigned)f2b(a[3])<<16);
  o.z = (unsigned)f2b(a[4]) | ((unsigned)f2b(a[5])<<16);
  o.w = (unsigned)f2b(a[6]) | ((unsigned)f2b(a[7])<<16);
  *(uint4*)(out + ((long)(b*L_ + (h0+py)*96 + (w0+px)))*DI + c0) = o;
}

// ================= K_soft =================
__global__ __launch_bounds__(256) void ksoft_kernel(
    const bfu* __restrict__ xB2, bfu* __restrict__ Ksoft)
{
  int p = blockIdx.x * 4 + (threadIdx.x >> 6);
  int lane = threadIdx.x & 63;
  float v = b2f(xB2[(long)p * CD + DI + lane]);
  float k = sigm(v);
  float s = k;
  #pragma unroll
  for (int o = 32; o; o >>= 1) s += __shfl_xor(s, o);
  Ksoft[((long)p << 6) + lane] = f2b(k / (s + 1e-6f));
}

// ================= proto partials =================
__global__ __launch_bounds__(256) void proto_part(
    const bfu* __restrict__ Ksf, const bfu* __restrict__ Vs, float* __restrict__ part)
{
  const int ch = blockIdx.x, bh = blockIdx.y;
  const int b = bh / NH, hh = bh % NH;
  __shared__ float Ks[32][68], Vt[32][68];
  const int tid = threadIdx.x, tx = tid & 15, ty = tid >> 4;
  float acc[4][4] = {};
  const int lbeg = ch * (L_/LSPLIT);
  for (int l0 = lbeg; l0 < lbeg + L_/LSPLIT; l0 += 32) {
    for (int v = tid; v < 512; v += 256) {
      int r = v >> 4, q = (v & 15) << 2;
      long lrow = (long)b * L_ + l0 + r;
      *(float4*)&Ks[r][q] = ld4(Ksf + (lrow << 6) + q);
      *(float4*)&Vt[r][q] = ld4(Vs + lrow * DI + hh*HD + q);
    }
    __syncthreads();
    #pragma unroll
    for (int kk = 0; kk < 32; ++kk) {
      float4 av = *(const float4*)&Ks[kk][ty*4];
      float4 bv = *(const float4*)&Vt[kk][tx*4];
      acc[0][0] += av.x*bv.x; acc[0][1] += av.x*bv.y; acc[0][2] += av.x*bv.z; acc[0][3] += av.x*bv.w;
      acc[1][0] += av.y*bv.x; acc[1][1] += av.y*bv.y; acc[1][2] += av.y*bv.z; acc[1][3] += av.y*bv.w;
      acc[2][0] += av.z*bv.x; acc[2][1] += av.z*bv.y; acc[2][2] += av.z*bv.z; acc[2][3] += av.z*bv.w;
      acc[3][0] += av.w*bv.x; acc[3][1] += av.w*bv.y; acc[3][2] += av.w*bv.z; acc[3][3] += av.w*bv.w;
    }
    __syncthreads();
  }
  float* dst = part + ((long)bh*LSPLIT + ch) * 4096;
  #pragma unroll
  for (int i = 0; i < 4; ++i)
    *(float4*)(dst + (ty*4+i)*64 + tx*4) = make_float4(acc[i][0],acc[i][1],acc[i][2],acc[i][3]);
}

__global__ __launch_bounds__(256) void reduce_proto(
    const float* __restrict__ part, float* __restrict__ proto)
{
  int idx = blockIdx.x * 256 + threadIdx.x;
  int bh = idx >> 12, sd = idx & 4095;
  const float* p = part + ((long)bh*LSPLIT)*4096 + sd;
  float s = 0.f;
  #pragma unroll
  for (int c = 0; c < LSPLIT; ++c) s += p[c*4096];
  proto[idx] = s;
}

// ================= flash PV (max-free streaming softmax) =================
__global__ __launch_bounds__(256) void flashpv(
    const float* __restrict__ proto, const bfu* __restrict__ Vs,
    float* __restrict__ pacc_part, float* __restrict__ dsum_part)
{
  const int ch = blockIdx.x, bh = blockIdx.y;
  const int b = bh / NH, hh = bh % NH;
  __shared__ float Pt[64][68];
  __shared__ float Vt[32][68];
  __shared__ float Ptl[32][68];
  const int tid = threadIdx.x, tx = tid & 15, ty = tid >> 4;
  for (int v = tid; v < 1024; v += 256) {
    int r = v >> 4, q = (v & 15) << 2;
    *(float4*)&Pt[r][q] = *(const float4*)(proto + ((long)bh << 12) + (r << 6) + q);
  }
  float pacc[4][4] = {};
  float dsum[4] = {};
  const int lbeg = ch * (L_/LSPLIT);
  for (int l0 = lbeg; l0 < lbeg + L_/LSPLIT; l0 += 32) {
    __syncthreads();
    for (int v = tid; v < 512; v += 256) {
      int r = v >> 4, q = (v & 15) << 2;
      *(float4*)&Vt[r][q] = ld4(Vs + ((long)b * L_ + l0 + r) * DI + hh*HD + q);
    }
    __syncthreads();
    #pragma unroll
    for (int h2 = 0; h2 < 2; ++h2) {
      int lc = tx + (h2 << 4);
      float s0=0.f, s1=0.f, s2=0.f, s3=0.f;
      #pragma unroll
      for (int d = 0; d < 64; ++d) {
        float vd = Vt[lc][d];
        s0 += Pt[ty*4+0][d]*vd; s1 += Pt[ty*4+1][d]*vd;
        s2 += Pt[ty*4+2][d]*vd; s3 += Pt[ty*4+3][d]*vd;
      }
      Ptl[lc][ty*4+0] = __expf(s0*SCALE_);
      Ptl[lc][ty*4+1] = __expf(s1*SCALE_);
      Ptl[lc][ty*4+2] = __expf(s2*SCALE_);
      Ptl[lc][ty*4+3] = __expf(s3*SCALE_);
    }
    __syncthreads();
    #pragma unroll
    for (int kk = 0; kk < 32; ++kk) {
      float4 av = *(const float4*)&Ptl[kk][ty*4];
      float4 bv = *(const float4*)&Vt[kk][tx*4];
      pacc[0][0] += av.x*bv.x; pacc[0][1] += av.x*bv.y; pacc[0][2] += av.x*bv.z; pacc[0][3] += av.x*bv.w;
      pacc[1][0] += av.y*bv.x; pacc[1][1] += av.y*bv.y; pacc[1][2] += av.y*bv.z; pacc[1][3] += av.y*bv.w;
      pacc[2][0] += av.z*bv.x; pacc[2][1] += av.z*bv.y; pacc[2][2] += av.z*bv.z; pacc[2][3] += av.z*bv.w;
      pacc[3][0] += av.w*bv.x; pacc[3][1] += av.w*bv.y; pacc[3][2] += av.w*bv.z; pacc[3][3] += av.w*bv.w;
      dsum[0] += av.x; dsum[1] += av.y; dsum[2] += av.z; dsum[3] += av.w;
    }
  }
  float* dst = pacc_part + ((long)bh*LSPLIT + ch) * 4096;
  #pragma unroll
  for (int i = 0; i < 4; ++i)
    *(float4*)(dst + (ty*4+i)*64 + tx*4) = make_float4(pacc[i][0],pacc[i][1],pacc[i][2],pacc[i][3]);
  if (tx == 0) {
    #pragma unroll
    for (int i = 0; i < 4; ++i)
      dsum_part[((long)bh*LSPLIT + ch)*64 + ty*4 + i] = dsum[i];
  }
}

// ================= reduce flash partials -> R2t [b][n=hh*64+d][k=s] bf16 =================
__global__ __launch_bounds__(256) void reduce_R2(
    const float* __restrict__ pacc_part, const float* __restrict__ dsum_part,
    bfu* __restrict__ R2t)
{
  int idx = blockIdx.x * 256 + threadIdx.x;   // 48*4096
  int bh = idx >> 12, s = (idx >> 6) & 63, d = idx & 63;
  int b = bh / NH, hh = bh % NH;
  float pa = 0.f, ds = 0.f;
  #pragma unroll
  for (int c = 0; c < LSPLIT; ++c) {
    pa += pacc_part[((long)bh*LSPLIT + c)*4096 + (s<<6) + d];
    ds += dsum_part[((long)bh*LSPLIT + c)*64 + s];
  }
  R2t[(((long)b*DI) + hh*HD + d)*64 + s] = f2b(pa / ds);
}

// ================= y = fine + V*D ; LN ; *z =================
__global__ __launch_bounds__(128) void ln_kernel(
    const bfu* __restrict__ fine, const bfu* __restrict__ xB2,
    const bfu* __restrict__ z, const float* __restrict__ Dv,
    const float* __restrict__ ln_g, const float* __restrict__ ln_b,
    bfu* __restrict__ yn)
{
  const int p = blockIdx.x;
  const int tid = threadIdx.x;
  __shared__ float sh[2], sh2[2];
  float y[3]; float s = 0.f, ss = 0.f;
  #pragma unroll
  for (int k = 0; k < 3; ++k) {
    int c = tid + (k << 7);
    float f = b2f(fine[(long)p*DI + c]) + b2f(xB2[(long)p*CD + c]) * Dv[c >> 6];
    y[k] = f; s += f; ss += f*f;
  }
  #pragma unroll
  for (int o = 32; o; o >>= 1) { s += __shfl_xor(s, o); ss += __shfl_xor(ss, o); }
  if ((tid & 63) == 0) { sh[tid >> 6] = s; sh2[tid >> 6] = ss; }
  __syncthreads();
  s = sh[0] + sh[1]; ss = sh2[0] + sh2[1];
  float mu = s * (1.f/384.f);
  float var = ss * (1.f/384.f) - mu*mu;
  float rs = rsqrtf(var + 1e-5f);
  #pragma unroll
  for (int k = 0; k < 3; ++k) {
    int c = tid + (k << 7);
    float o2 = (y[k] - mu) * rs * ln_g[c] + ln_b[c];
    yn[(long)p*DI + c] = f2b(o2 * b2f(z[(long)p*DI + c]));
  }
}

extern "C" void kernel_launch(void* const* d_in, const int* in_sizes, int n_in,
                              void* d_out, int out_size, void* d_ws, size_t ws_size,
                              hipStream_t stream) {
  const float* u      = (const float*)d_in[0];
  const float* W_in   = (const float*)d_in[1];
  const float* conv_w = (const float*)d_in[2];
  const float* conv_b = (const float*)d_in[3];
  const float* dw_w   = (const float*)d_in[4];
  const float* dw_b   = (const float*)d_in[5];
  const float* pw_w   = (const float*)d_in[6];
  const float* pw_b   = (const float*)d_in[7];
  const float* Dv     = (const float*)d_in[8];
  const float* ln_g   = (const float*)d_in[9];
  const float* ln_b   = (const float*)d_in[10];
  const float* W_out  = (const float*)d_in[11];
  float* out = (float*)d_out;

  bfu* z_bf = (bfu*)d_out;      // M_*384 bf16 == out_size*4 bytes, dead before final write

  char* ws = (char*)d_ws;
  size_t off = 0;
  bfu* xB_bf   = (bfu*)(ws + off); off += (size_t)M_*CD*2;    // gemm1 cols 384.. ; later fine
  bfu* xB2_bf  = (bfu*)(ws + off); off += (size_t)M_*CD*2;    // conv3 out, live to LN
  bfu* xloc_bf = (bfu*)(ws + off); off += (size_t)M_*DI*2;    // conv5 out; later yn
  bfu* Vs_bf   = (bfu*)(ws + off); off += (size_t)M_*DI*2;
  bfu* Ksf_bf  = (bfu*)(ws + off); off += (size_t)M_*DS*2;
  bfu* Wt_in   = (bfu*)(ws + off); off += (size_t)832*192*2;
  bfu* pw_bf   = (bfu*)(ws + off); off += (size_t)384*384*2;
  bfu* Wt_out  = (bfu*)(ws + off); off += (size_t)192*384*2;
  bfu* R2t     = (bfu*)(ws + off); off += (size_t)8*DI*64*2;
  float* part  = (float*)(ws + off); off += (size_t)48*LSPLIT*4096*4;
  float* dsum  = (float*)(ws + off); off += (size_t)48*LSPLIT*64*4;
  float* proto = (float*)(ws + off); off += (size_t)48*4096*4;

  bfu* fine_bf = xB_bf;
  bfu* yn_bf   = xloc_bf;

  // 0) weight prep
  prep_w<<<1488, 256, 0, stream>>>(W_in, pw_w, W_out, Wt_in, pw_bf, Wt_out);
  // 1) zxB = u @ W_in  (MFMA; A=f32 u converted during staging)
  gemm_mfma<false,float,bfu,bfu><<<dim3(13,576,1), 256, 0, stream>>>(
      u, Wt_in, nullptr, z_bf, xB_bf, 192, 384, 384, 448, 0, 0, 0);
  // 2) depthwise 3x3 + silu (LDS tiled)
  conv3x3_t<<<dim3(36,56,8), 256, 0, stream>>>(xB_bf, conv_w, conv_b, xB2_bf);
  // 2b) K_soft
  ksoft_kernel<<<M_/4, 256, 0, stream>>>(xB2_bf, Ksf_bf);
  // 3) depthwise 5x5 (LDS tiled)
  conv5x5_t<<<dim3(36,48,8), 256, 0, stream>>>(xB2_bf, dw_w, dw_b, xloc_bf);
  // 4) pointwise: Vs = xloc @ pw_w^T + pw_b (MFMA)
  gemm_mfma<true,bfu,bfu,bfu><<<dim3(6,576,1), 256, 0, stream>>>(
      xloc_bf, pw_bf, pw_b, Vs_bf, (bfu*)nullptr, 384, 1<<30, 384, 0, 0, 0, 0);
  // 5) proto
  proto_part<<<dim3(LSPLIT,48), 256, 0, stream>>>(Ksf_bf, Vs_bf, part);
  reduce_proto<<<768, 256, 0, stream>>>(part, proto);
  // 6) flash attention partials + reduce -> R2t (bf16 [b][n][k])
  flashpv<<<dim3(LSPLIT,48), 256, 0, stream>>>(proto, Vs_bf, part, dsum);
  reduce_R2<<<768, 256, 0, stream>>>(part, dsum, R2t);
  // 7) fine = Ksoft @ refined^T (MFMA, batched over b, K=64)
  gemm_mfma<false,bfu,bfu,bfu><<<dim3(6,72,8), 256, 0, stream>>>(
      Ksf_bf, R2t, nullptr, fine_bf, (bfu*)nullptr, 64, 1<<30, 384, 0,
      (long)L_*64, (long)DI*64, (long)L_*384);
  // 8) y = fine + V*D ; LN ; *z
  ln_kernel<<<M_, 128, 0, stream>>>(fine_bf, xB2_bf, z_bf, Dv, ln_g, ln_b, yn_bf);
  // 9) out = yn @ W_out (MFMA, f32 out)
  gemm_mfma<false,bfu,float,float><<<dim3(3,576,1), 256, 0, stream>>>(
      yn_bf, Wt_out, nullptr, out, (float*)nullptr, 384, 1<<30, 192, 0, 0, 0, 0);
}

// Round 5
// 584.175 us; speedup vs baseline: 4.2681x; 1.6015x over previous
//
#include <hip/hip_runtime.h>

#define B_ 8
#define H_ 96
#define W_ 96
#define L_ (H_*W_)          // 9216
#define M_ (B_*L_)          // 73728
#define DM 192
#define DI 384
#define DS 64
#define CD 448              // DI+DS
#define NH 6
#define HD 64
#define SCALE_ 0.125f
#define LSPLIT 16           // l-chunks for attention partials (768 blocks)

typedef unsigned short bfu;
typedef __attribute__((ext_vector_type(8))) short bf16x8;
typedef __attribute__((ext_vector_type(8))) unsigned short u16x8;
typedef __attribute__((ext_vector_type(4))) float f32x4;

__device__ __forceinline__ float sigm(float x){ return 1.f/(1.f+__expf(-x)); }
__device__ __forceinline__ float b2f(bfu h){ return __uint_as_float(((unsigned)h)<<16); }
__device__ __forceinline__ bfu f2b(float f){
  unsigned x = __float_as_uint(f);
  return (bfu)((x + 0x7fffu + ((x>>16)&1u)) >> 16);
}
__device__ __forceinline__ float4 ld4(const float* p){ return *(const float4*)p; }
__device__ __forceinline__ float4 ld4(const bfu* p){
  ushort4 u = *(const ushort4*)p;
  return make_float4(b2f(u.x), b2f(u.y), b2f(u.z), b2f(u.w));
}
// stage 8 elements (16B of bf16) into LDS
__device__ __forceinline__ void stage8(const bfu* src, bfu* dst){
  *(uint4*)dst = *(const uint4*)src;
}
__device__ __forceinline__ void stage8(const float* src, bfu* dst){
  float4 f0 = *(const float4*)src, f1 = *(const float4*)(src+4);
  ushort4 a; a.x=f2b(f0.x); a.y=f2b(f0.y); a.z=f2b(f0.z); a.w=f2b(f0.w);
  ushort4 b; b.x=f2b(f1.x); b.y=f2b(f1.y); b.z=f2b(f1.z); b.w=f2b(f1.w);
  *(ushort4*)dst = a; *(ushort4*)(dst+4) = b;
}
__device__ __forceinline__ void stel(float* p, float v){ *p = v; }
__device__ __forceinline__ void stel(bfu* p, float v){ *p = f2b(v); }

// XOR swizzle: element offset of 8-elem chunk `sg` in row `r` (16B granules)
#define SWZ(r, sg) ((((sg) ^ ((r)&7)) << 3))
// element offset of scalar col c in row r under the same swizzle
#define SWZE(r, c) (SWZ(r, (c)>>3) + ((c)&7))

// ================= MFMA GEMM: C[m,n] = sum_k A[m,k]*Bw[n,k] (+bias) =================
template<bool BIAS, class TA, class TC0, class TC1>
__global__ __launch_bounds__(256) void gemm_mfma(
    const TA* __restrict__ A, const bfu* __restrict__ Bw,
    const float* __restrict__ bias,
    TC0* __restrict__ C0, TC1* __restrict__ C1,
    int K, int splitN, int ldc0, int ldc1,
    long sA, long sB, long sC)
{
  __shared__ bfu As[128][72];
  __shared__ bfu Bs[64][72];
  const int tid = threadIdx.x;
  const int n0 = blockIdx.x*64, m0 = blockIdx.y*128, zb = blockIdx.z;
  A  += (long)zb*sA;
  Bw += (long)zb*sB;
  const int wave = tid>>6, lane = tid&63;
  const int wr = wave>>1, wc = wave&1;
  const int lr = lane&15, lk = lane>>4;
  f32x4 acc[4][2];
  #pragma unroll
  for (int mr=0;mr<4;++mr)
    #pragma unroll
    for (int nr=0;nr<2;++nr){ acc[mr][nr][0]=0.f; acc[mr][nr][1]=0.f; acc[mr][nr][2]=0.f; acc[mr][nr][3]=0.f; }
  for (int k0 = 0; k0 < K; k0 += 64) {
    #pragma unroll
    for (int i = 0; i < 4; ++i) {
      int seg = i*256 + tid;
      int r = seg>>3, sg = seg&7;
      stage8(A + (long)(m0+r)*K + k0 + sg*8, &As[r][sg*8]);
    }
    #pragma unroll
    for (int i = 0; i < 2; ++i) {
      int seg = i*256 + tid;
      int r = seg>>3, sg = seg&7;
      stage8(Bw + (long)(n0+r)*K + k0 + sg*8, &Bs[r][sg*8]);
    }
    __syncthreads();
    #pragma unroll
    for (int ks = 0; ks < 2; ++ks) {
      bf16x8 af[4], bfr[2];
      #pragma unroll
      for (int mr=0; mr<4; ++mr) af[mr]  = *(const bf16x8*)&As[wr*64+mr*16+lr][ks*32+lk*8];
      #pragma unroll
      for (int nr=0; nr<2; ++nr) bfr[nr] = *(const bf16x8*)&Bs[wc*32+nr*16+lr][ks*32+lk*8];
      #pragma unroll
      for (int mr=0; mr<4; ++mr)
        #pragma unroll
        for (int nr=0; nr<2; ++nr)
          acc[mr][nr] = __builtin_amdgcn_mfma_f32_16x16x32_bf16(af[mr], bfr[nr], acc[mr][nr], 0,0,0);
    }
    __syncthreads();
  }
  #pragma unroll
  for (int mr=0; mr<4; ++mr) {
    #pragma unroll
    for (int nr=0; nr<2; ++nr) {
      const int col = n0 + wc*32 + nr*16 + lr;
      const float badd = BIAS ? bias[col] : 0.f;
      #pragma unroll
      for (int i=0;i<4;++i) {
        const int row = m0 + wr*64 + mr*16 + lk*4 + i;
        const float v = acc[mr][nr][i] + badd;
        if (col < splitN) stel(C0 + (long)zb*sC + (long)row*ldc0 + col, v);
        else              stel(C1 + (long)row*ldc1 + (col - splitN), v);
      }
    }
  }
}

// ================= weight prep =================
__global__ __launch_bounds__(256) void prep_w(
    const float* __restrict__ W_in, const float* __restrict__ pw_w,
    const float* __restrict__ W_out,
    bfu* __restrict__ Wt_in, bfu* __restrict__ pw_bf, bfu* __restrict__ Wt_out)
{
  int i = blockIdx.x*256 + threadIdx.x;
  const int n1 = 832*192, n2 = n1 + 384*384, n3 = n2 + 192*384;
  if (i < n1)      { int n=i/192, k=i%192; Wt_in[i]  = f2b(W_in[k*832+n]); }
  else if (i < n2) { int j=i-n1;           pw_bf[j]  = f2b(pw_w[j]); }
  else if (i < n3) { int j=i-n2; int n=j/384, k=j%384; Wt_out[j] = f2b(W_out[k*192+n]); }
}

// ================= depthwise 3x3 + silu =================
__global__ __launch_bounds__(256) void conv3x3_t(
    const bfu* __restrict__ xB, const float* __restrict__ cw,
    const float* __restrict__ cb, bfu* __restrict__ out)
{
  const int tile = blockIdx.x, c0 = blockIdx.y*8, b = blockIdx.z;
  const int h0 = (tile/6)*16, w0 = (tile%6)*16;
  __shared__ alignas(16) bfu tl[18][18][8];
  __shared__ float wl[8][9];
  const int tid = threadIdx.x;
  if (tid < 72) wl[tid/9][tid%9] = cw[(c0 + tid/9)*9 + tid%9];
  for (int i = tid; i < 324; i += 256) {
    int y = i/18, x = i%18;
    int gh = h0+y-1, gw = w0+x-1;
    uint4 v = make_uint4(0,0,0,0);
    if ((unsigned)gh < 96u && (unsigned)gw < 96u)
      v = *(const uint4*)(xB + ((long)(b*L_ + gh*96+gw))*CD + c0);
    *(uint4*)&tl[y][x][0] = v;
  }
  __syncthreads();
  const int px = tid & 15, py = tid >> 4;
  float a[8];
  #pragma unroll
  for (int j=0;j<8;++j) a[j] = cb[c0+j];
  #pragma unroll
  for (int dh=0; dh<3; ++dh)
    #pragma unroll
    for (int dw=0; dw<3; ++dw) {
      uint4 r = *(const uint4*)&tl[py+dh][px+dw][0];
      int t = dh*3+dw;
      a[0] += __uint_as_float(r.x<<16)        * wl[0][t];
      a[1] += __uint_as_float(r.x&0xffff0000u)* wl[1][t];
      a[2] += __uint_as_float(r.y<<16)        * wl[2][t];
      a[3] += __uint_as_float(r.y&0xffff0000u)* wl[3][t];
      a[4] += __uint_as_float(r.z<<16)        * wl[4][t];
      a[5] += __uint_as_float(r.z&0xffff0000u)* wl[5][t];
      a[6] += __uint_as_float(r.w<<16)        * wl[6][t];
      a[7] += __uint_as_float(r.w&0xffff0000u)* wl[7][t];
    }
  #pragma unroll
  for (int j=0;j<8;++j) a[j] = a[j]*sigm(a[j]);
  uint4 o;
  o.x = (unsigned)f2b(a[0]) | ((unsigned)f2b(a[1])<<16);
  o.y = (unsigned)f2b(a[2]) | ((unsigned)f2b(a[3])<<16);
  o.z = (unsigned)f2b(a[4]) | ((unsigned)f2b(a[5])<<16);
  o.w = (unsigned)f2b(a[6]) | ((unsigned)f2b(a[7])<<16);
  *(uint4*)(out + ((long)(b*L_ + (h0+py)*96 + (w0+px)))*CD + c0) = o;
}

// ================= depthwise 5x5 =================
__global__ __launch_bounds__(256) void conv5x5_t(
    const bfu* __restrict__ xin, const float* __restrict__ cw,
    const float* __restrict__ cb, bfu* __restrict__ out)
{
  const int tile = blockIdx.x, c0 = blockIdx.y*8, b = blockIdx.z;
  const int h0 = (tile/6)*16, w0 = (tile%6)*16;
  __shared__ alignas(16) bfu tl[20][20][8];
  __shared__ float wl[8][25];
  const int tid = threadIdx.x;
  if (tid < 200) wl[tid/25][tid%25] = cw[(c0 + tid/25)*25 + tid%25];
  for (int i = tid; i < 400; i += 256) {
    int y = i/20, x = i%20;
    int gh = h0+y-2, gw = w0+x-2;
    uint4 v = make_uint4(0,0,0,0);
    if ((unsigned)gh < 96u && (unsigned)gw < 96u)
      v = *(const uint4*)(xin + ((long)(b*L_ + gh*96+gw))*CD + c0);
    *(uint4*)&tl[y][x][0] = v;
  }
  __syncthreads();
  const int px = tid & 15, py = tid >> 4;
  float a[8];
  #pragma unroll
  for (int j=0;j<8;++j) a[j] = cb[c0+j];
  #pragma unroll
  for (int dh=0; dh<5; ++dh)
    #pragma unroll
    for (int dw=0; dw<5; ++dw) {
      uint4 r = *(const uint4*)&tl[py+dh][px+dw][0];
      int t = dh*5+dw;
      a[0] += __uint_as_float(r.x<<16)        * wl[0][t];
      a[1] += __uint_as_float(r.x&0xffff0000u)* wl[1][t];
      a[2] += __uint_as_float(r.y<<16)        * wl[2][t];
      a[3] += __uint_as_float(r.y&0xffff0000u)* wl[3][t];
      a[4] += __uint_as_float(r.z<<16)        * wl[4][t];
      a[5] += __uint_as_float(r.z&0xffff0000u)* wl[5][t];
      a[6] += __uint_as_float(r.w<<16)        * wl[6][t];
      a[7] += __uint_as_float(r.w&0xffff0000u)* wl[7][t];
    }
  uint4 o;
  o.x = (unsigned)f2b(a[0]) | ((unsigned)f2b(a[1])<<16);
  o.y = (unsigned)f2b(a[2]) | ((unsigned)f2b(a[3])<<16);
  o.z = (unsigned)f2b(a[4]) | ((unsigned)f2b(a[5])<<16);
  o.w = (unsigned)f2b(a[6]) | ((unsigned)f2b(a[7])<<16);
  *(uint4*)(out + ((long)(b*L_ + (h0+py)*96 + (w0+px)))*DI + c0) = o;
}

// ================= K_soft =================
__global__ __launch_bounds__(256) void ksoft_kernel(
    const bfu* __restrict__ xB2, bfu* __restrict__ Ksoft)
{
  int p = blockIdx.x * 4 + (threadIdx.x >> 6);
  int lane = threadIdx.x & 63;
  float v = b2f(xB2[(long)p * CD + DI + lane]);
  float k = sigm(v);
  float s = k;
  #pragma unroll
  for (int o = 32; o; o >>= 1) s += __shfl_xor(s, o);
  Ksoft[((long)p << 6) + lane] = f2b(k / (s + 1e-6f));
}

// ================= proto partials (MFMA): proto[s][d] += K[l][s]*V[l][d] =================
__global__ __launch_bounds__(256) void proto_mfma(
    const bfu* __restrict__ Ksf, const bfu* __restrict__ Vs, float* __restrict__ part)
{
  const int ch = blockIdx.x, bh = blockIdx.y;
  const int b = bh / NH, hh = bh % NH;
  __shared__ alignas(16) bfu Kst[64][72];   // K^T [s][l], swizzled
  __shared__ alignas(16) bfu Vtt[64][72];   // V^T [d][l], swizzled
  const int tid = threadIdx.x;
  const int wave = tid>>6, lane = tid&63;
  const int wr = wave>>1, wc = wave&1;
  const int lr = lane&15, lk = lane>>4;
  f32x4 acc[2][2];
  #pragma unroll
  for (int mr=0;mr<2;++mr)
    #pragma unroll
    for (int nr=0;nr<2;++nr){ acc[mr][nr][0]=0.f; acc[mr][nr][1]=0.f; acc[mr][nr][2]=0.f; acc[mr][nr][3]=0.f; }
  const int lbeg = ch * (L_/LSPLIT);
  for (int l0 = lbeg; l0 < lbeg + L_/LSPLIT; l0 += 64) {
    __syncthreads();
    #pragma unroll
    for (int i=0;i<2;++i) {
      const int li = tid&63, sg = (tid>>6) + i*4;
      const long lrow = (long)b*L_ + l0 + li;
      u16x8 kv = *(const u16x8*)(Ksf + (lrow<<6) + sg*8);
      u16x8 vv = *(const u16x8*)(Vs + lrow*DI + hh*HD + sg*8);
      #pragma unroll
      for (int j=0;j<8;++j) {
        int r = sg*8+j;
        Kst[r][SWZE(r, li)] = kv[j];
        Vtt[r][SWZE(r, li)] = vv[j];
      }
    }
    __syncthreads();
    #pragma unroll
    for (int ks=0; ks<2; ++ks) {
      bf16x8 af[2], bfr[2];
      #pragma unroll
      for (int mr=0;mr<2;++mr){ int r = wr*32+mr*16+lr; af[mr]  = *(const bf16x8*)&Kst[r][SWZ(r, ks*4+lk)]; }
      #pragma unroll
      for (int nr=0;nr<2;++nr){ int r = wc*32+nr*16+lr; bfr[nr] = *(const bf16x8*)&Vtt[r][SWZ(r, ks*4+lk)]; }
      #pragma unroll
      for (int mr=0;mr<2;++mr)
        #pragma unroll
        for (int nr=0;nr<2;++nr)
          acc[mr][nr] = __builtin_amdgcn_mfma_f32_16x16x32_bf16(af[mr], bfr[nr], acc[mr][nr], 0,0,0);
    }
  }
  float* dst = part + ((long)bh*LSPLIT + ch) * 4096;
  #pragma unroll
  for (int mr=0;mr<2;++mr)
    #pragma unroll
    for (int nr=0;nr<2;++nr)
      #pragma unroll
      for (int i=0;i<4;++i) {
        int row = wr*32+mr*16+lk*4+i, col = wc*32+nr*16+lr;
        dst[row*64+col] = acc[mr][nr][i];
      }
}

// ================= reduce proto chunks -> bf16 =================
__global__ __launch_bounds__(256) void reduce_proto(
    const float* __restrict__ part, bfu* __restrict__ proto)
{
  int idx = blockIdx.x * 256 + threadIdx.x;
  int bh = idx >> 12, sd = idx & 4095;
  const float* p = part + ((long)bh*LSPLIT)*4096 + sd;
  float s = 0.f;
  #pragma unroll
  for (int c = 0; c < LSPLIT; ++c) s += p[c*4096];
  proto[idx] = f2b(s);
}

// ================= flash PV (MFMA): S=proto@V^T, P=exp(S*scale), pacc+=P@V =================
__global__ __launch_bounds__(256) void flashpv_mfma(
    const bfu* __restrict__ proto, const bfu* __restrict__ Vs,
    float* __restrict__ pacc_part, float* __restrict__ dsum_part)
{
  const int ch = blockIdx.x, bh = blockIdx.y;
  const int b = bh / NH, hh = bh % NH;
  __shared__ alignas(16) bfu Pt[64][72];    // proto [s][d], swizzled
  __shared__ alignas(16) bfu Vt[64][72];    // V [l][d], swizzled
  __shared__ alignas(16) bfu Vtt[64][72];   // V^T [d][l], swizzled
  __shared__ alignas(16) bfu Ptl[64][72];   // P [s][l], swizzled
  __shared__ float dsh[2][64];
  const int tid = threadIdx.x;
  const int wave = tid>>6, lane = tid&63;
  const int wr = wave>>1, wc = wave&1;
  const int lr = lane&15, lk = lane>>4;
  // stage proto once
  {
    const bfu* src = proto + ((long)bh<<12);
    #pragma unroll
    for (int i=0;i<2;++i) {
      const int li = tid&63, sg = (tid>>6) + i*4;
      *(uint4*)&Pt[li][SWZ(li, sg)] = *(const uint4*)(src + li*64 + sg*8);
    }
  }
  f32x4 pacc[2][2];
  #pragma unroll
  for (int mr=0;mr<2;++mr)
    #pragma unroll
    for (int nr=0;nr<2;++nr){ pacc[mr][nr][0]=0.f; pacc[mr][nr][1]=0.f; pacc[mr][nr][2]=0.f; pacc[mr][nr][3]=0.f; }
  float ds[8] = {};
  const int lbeg = ch * (L_/LSPLIT);
  for (int l0 = lbeg; l0 < lbeg + L_/LSPLIT; l0 += 64) {
    __syncthreads();
    #pragma unroll
    for (int i=0;i<2;++i) {
      const int li = tid&63, sg = (tid>>6) + i*4;
      u16x8 vv = *(const u16x8*)(Vs + ((long)b*L_ + l0 + li)*DI + hh*HD + sg*8);
      *(u16x8*)&Vt[li][SWZ(li, sg)] = vv;
      #pragma unroll
      for (int j=0;j<8;++j) { int r = sg*8+j; Vtt[r][SWZE(r, li)] = vv[j]; }
    }
    __syncthreads();
    // S-phase
    f32x4 sacc[2][2];
    #pragma unroll
    for (int mr=0;mr<2;++mr)
      #pragma unroll
      for (int nr=0;nr<2;++nr){ sacc[mr][nr][0]=0.f; sacc[mr][nr][1]=0.f; sacc[mr][nr][2]=0.f; sacc[mr][nr][3]=0.f; }
    #pragma unroll
    for (int ks=0; ks<2; ++ks) {
      bf16x8 af[2], bfr[2];
      #pragma unroll
      for (int mr=0;mr<2;++mr){ int r = wr*32+mr*16+lr; af[mr]  = *(const bf16x8*)&Pt[r][SWZ(r, ks*4+lk)]; }
      #pragma unroll
      for (int nr=0;nr<2;++nr){ int r = wc*32+nr*16+lr; bfr[nr] = *(const bf16x8*)&Vt[r][SWZ(r, ks*4+lk)]; }
      #pragma unroll
      for (int mr=0;mr<2;++mr)
        #pragma unroll
        for (int nr=0;nr<2;++nr)
          sacc[mr][nr] = __builtin_amdgcn_mfma_f32_16x16x32_bf16(af[mr], bfr[nr], sacc[mr][nr], 0,0,0);
    }
    // exp + P store + dsum partials
    #pragma unroll
    for (int mr=0;mr<2;++mr)
      #pragma unroll
      for (int nr=0;nr<2;++nr)
        #pragma unroll
        for (int i=0;i<4;++i) {
          int row = wr*32+mr*16+lk*4+i, col = wc*32+nr*16+lr;
          float p = __expf(sacc[mr][nr][i]*SCALE_);
          ds[mr*4+i] += p;
          Ptl[row][SWZE(row, col)] = f2b(p);
        }
    __syncthreads();
    // PV-phase
    #pragma unroll
    for (int ks=0; ks<2; ++ks) {
      bf16x8 af2[2], bf2[2];
      #pragma unroll
      for (int mr=0;mr<2;++mr){ int r = wr*32+mr*16+lr; af2[mr] = *(const bf16x8*)&Ptl[r][SWZ(r, ks*4+lk)]; }
      #pragma unroll
      for (int nr=0;nr<2;++nr){ int r = wc*32+nr*16+lr; bf2[nr] = *(const bf16x8*)&Vtt[r][SWZ(r, ks*4+lk)]; }
      #pragma unroll
      for (int mr=0;mr<2;++mr)
        #pragma unroll
        for (int nr=0;nr<2;++nr)
          pacc[mr][nr] = __builtin_amdgcn_mfma_f32_16x16x32_bf16(af2[mr], bf2[nr], pacc[mr][nr], 0,0,0);
    }
  }
  // write pacc partials
  float* dst = pacc_part + ((long)bh*LSPLIT + ch) * 4096;
  #pragma unroll
  for (int mr=0;mr<2;++mr)
    #pragma unroll
    for (int nr=0;nr<2;++nr)
      #pragma unroll
      for (int i=0;i<4;++i) {
        int row = wr*32+mr*16+lk*4+i, col = wc*32+nr*16+lr;
        dst[row*64+col] = pacc[mr][nr][i];
      }
  // dsum: reduce over the 16 col-lanes, then combine col-halves via LDS
  #pragma unroll
  for (int o=1;o<16;o<<=1)
    #pragma unroll
    for (int j=0;j<8;++j) ds[j] += __shfl_xor(ds[j], o);
  if (lr == 0) {
    #pragma unroll
    for (int mr=0;mr<2;++mr)
      #pragma unroll
      for (int i=0;i<4;++i)
        dsh[wc][wr*32+mr*16+lk*4+i] = ds[mr*4+i];
  }
  __syncthreads();
  if (tid < 64)
    dsum_part[((long)bh*LSPLIT + ch)*64 + tid] = dsh[0][tid] + dsh[1][tid];
}

// ================= reduce flash partials -> R2t [b][n=hh*64+d][k=s] bf16 =================
__global__ __launch_bounds__(256) void reduce_R2(
    const float* __restrict__ pacc_part, const float* __restrict__ dsum_part,
    bfu* __restrict__ R2t)
{
  int idx = blockIdx.x * 256 + threadIdx.x;   // 48*4096
  int bh = idx >> 12, s = (idx >> 6) & 63, d = idx & 63;
  int b = bh / NH, hh = bh % NH;
  float pa = 0.f, dsv = 0.f;
  #pragma unroll
  for (int c = 0; c < LSPLIT; ++c) {
    pa += pacc_part[((long)bh*LSPLIT + c)*4096 + (s<<6) + d];
    dsv += dsum_part[((long)bh*LSPLIT + c)*64 + s];
  }
  R2t[(((long)b*DI) + hh*HD + d)*64 + s] = f2b(pa / dsv);
}

// ================= y = fine + V*D ; LN ; *z =================
__global__ __launch_bounds__(128) void ln_kernel(
    const bfu* __restrict__ fine, const bfu* __restrict__ xB2,
    const bfu* __restrict__ z, const float* __restrict__ Dv,
    const float* __restrict__ ln_g, const float* __restrict__ ln_b,
    bfu* __restrict__ yn)
{
  const int p = blockIdx.x;
  const int tid = threadIdx.x;
  __shared__ float sh[2], sh2[2];
  float y[3]; float s = 0.f, ss = 0.f;
  #pragma unroll
  for (int k = 0; k < 3; ++k) {
    int c = tid + (k << 7);
    float f = b2f(fine[(long)p*DI + c]) + b2f(xB2[(long)p*CD + c]) * Dv[c >> 6];
    y[k] = f; s += f; ss += f*f;
  }
  #pragma unroll
  for (int o = 32; o; o >>= 1) { s += __shfl_xor(s, o); ss += __shfl_xor(ss, o); }
  if ((tid & 63) == 0) { sh[tid >> 6] = s; sh2[tid >> 6] = ss; }
  __syncthreads();
  s = sh[0] + sh[1]; ss = sh2[0] + sh2[1];
  float mu = s * (1.f/384.f);
  float var = ss * (1.f/384.f) - mu*mu;
  float rs = rsqrtf(var + 1e-5f);
  #pragma unroll
  for (int k = 0; k < 3; ++k) {
    int c = tid + (k << 7);
    float o2 = (y[k] - mu) * rs * ln_g[c] + ln_b[c];
    yn[(long)p*DI + c] = f2b(o2 * b2f(z[(long)p*DI + c]));
  }
}

extern "C" void kernel_launch(void* const* d_in, const int* in_sizes, int n_in,
                              void* d_out, int out_size, void* d_ws, size_t ws_size,
                              hipStream_t stream) {
  const float* u      = (const float*)d_in[0];
  const float* W_in   = (const float*)d_in[1];
  const float* conv_w = (const float*)d_in[2];
  const float* conv_b = (const float*)d_in[3];
  const float* dw_w   = (const float*)d_in[4];
  const float* dw_b   = (const float*)d_in[5];
  const float* pw_w   = (const float*)d_in[6];
  const float* pw_b   = (const float*)d_in[7];
  const float* Dv     = (const float*)d_in[8];
  const float* ln_g   = (const float*)d_in[9];
  const float* ln_b   = (const float*)d_in[10];
  const float* W_out  = (const float*)d_in[11];
  float* out = (float*)d_out;

  bfu* z_bf = (bfu*)d_out;      // M_*384 bf16 == out_size*4 bytes, dead before final write

  char* ws = (char*)d_ws;
  size_t off = 0;
  bfu* xB_bf   = (bfu*)(ws + off); off += (size_t)M_*CD*2;   // gemm1 cols 384..; later fine
  bfu* xB2_bf  = (bfu*)(ws + off); off += (size_t)M_*CD*2;   // conv3 out, live to LN
  bfu* xloc_bf = (bfu*)(ws + off); off += (size_t)M_*DI*2;   // conv5 out; dead after step 4;
                                                             // part/dsum OVERLAY here (steps 5-6);
                                                             // re-written as yn at step 8
  bfu* Vs_bf   = (bfu*)(ws + off); off += (size_t)M_*DI*2;
  bfu* Ksf_bf  = (bfu*)(ws + off); off += (size_t)M_*DS*2;
  bfu* Wt_in   = (bfu*)(ws + off); off += (size_t)832*192*2;
  bfu* pw_bf   = (bfu*)(ws + off); off += (size_t)384*384*2;
  bfu* Wt_out  = (bfu*)(ws + off); off += (size_t)192*384*2;
  bfu* R2t     = (bfu*)(ws + off); off += (size_t)8*DI*64*2;
  bfu* proto_b = (bfu*)(ws + off); off += (size_t)48*4096*2;
  // total static: ~256.4 MB (< the ~261.5 MB known-good from round 3).
  // part (12.6 MB) + dsum (0.2 MB) overlay the dead xloc region (56.6 MB):
  float* part  = (float*)xloc_bf;                       // 48*LSPLIT*4096 f32
  float* dsum  = part + (size_t)48*LSPLIT*4096;         // 48*LSPLIT*64 f32

  bfu* fine_bf = xB_bf;
  bfu* yn_bf   = xloc_bf;

  // 0) weight prep
  prep_w<<<1488, 256, 0, stream>>>(W_in, pw_w, W_out, Wt_in, pw_bf, Wt_out);
  // 1) zxB = u @ W_in
  gemm_mfma<false,float,bfu,bfu><<<dim3(13,576,1), 256, 0, stream>>>(
      u, Wt_in, nullptr, z_bf, xB_bf, 192, 384, 384, 448, 0, 0, 0);
  // 2) depthwise 3x3 + silu
  conv3x3_t<<<dim3(36,56,8), 256, 0, stream>>>(xB_bf, conv_w, conv_b, xB2_bf);
  // 2b) K_soft
  ksoft_kernel<<<M_/4, 256, 0, stream>>>(xB2_bf, Ksf_bf);
  // 3) depthwise 5x5
  conv5x5_t<<<dim3(36,48,8), 256, 0, stream>>>(xB2_bf, dw_w, dw_b, xloc_bf);
  // 4) pointwise: Vs = xloc @ pw_w^T + pw_b  (last reader of xloc)
  gemm_mfma<true,bfu,bfu,bfu><<<dim3(6,576,1), 256, 0, stream>>>(
      xloc_bf, pw_bf, pw_b, Vs_bf, (bfu*)nullptr, 384, 1<<30, 384, 0, 0, 0, 0);
  // 5) proto (MFMA partials + reduce) — part now lives in xloc region
  proto_mfma<<<dim3(LSPLIT,48), 256, 0, stream>>>(Ksf_bf, Vs_bf, part);
  reduce_proto<<<768, 256, 0, stream>>>(part, proto_b);
  // 6) flash attention (MFMA) partials + reduce -> R2t
  flashpv_mfma<<<dim3(LSPLIT,48), 256, 0, stream>>>(proto_b, Vs_bf, part, dsum);
  reduce_R2<<<768, 256, 0, stream>>>(part, dsum, R2t);
  // 7) fine = Ksoft @ refined^T
  gemm_mfma<false,bfu,bfu,bfu><<<dim3(6,72,8), 256, 0, stream>>>(
      Ksf_bf, R2t, nullptr, fine_bf, (bfu*)nullptr, 64, 1<<30, 384, 0,
      (long)L_*64, (long)DI*64, (long)L_*384);
  // 8) y = fine + V*D ; LN ; *z  (yn overwrites xloc region — part/dsum dead)
  ln_kernel<<<M_, 128, 0, stream>>>(fine_bf, xB2_bf, z_bf, Dv, ln_g, ln_b, yn_bf);
  // 9) out = yn @ W_out
  gemm_mfma<false,bfu,float,float><<<dim3(3,576,1), 256, 0, stream>>>(
      yn_bf, Wt_out, nullptr, out, (float*)nullptr, 384, 1<<30, 192, 0, 0, 0, 0);
}

// Round 6
// 498.200 us; speedup vs baseline: 5.0047x; 1.1726x over previous
//
#include <hip/hip_runtime.h>

#define B_ 8
#define H_ 96
#define W_ 96
#define L_ (H_*W_)          // 9216
#define M_ (B_*L_)          // 73728
#define DM 192
#define DI 384
#define DS 64
#define CD 448              // DI+DS
#define NH 6
#define HD 64
#define SCALE_ 0.125f
#define LSPLIT 16           // l-chunks for attention partials (768 blocks)

typedef unsigned short bfu;
typedef __attribute__((ext_vector_type(8))) short bf16x8;
typedef __attribute__((ext_vector_type(8))) unsigned short u16x8;
typedef __attribute__((ext_vector_type(4))) float f32x4;

__device__ __forceinline__ float sigm(float x){ return 1.f/(1.f+__expf(-x)); }
__device__ __forceinline__ float b2f(bfu h){ return __uint_as_float(((unsigned)h)<<16); }
__device__ __forceinline__ bfu f2b(float f){
  unsigned x = __float_as_uint(f);
  return (bfu)((x + 0x7fffu + ((x>>16)&1u)) >> 16);
}
__device__ __forceinline__ float4 ld4(const float* p){ return *(const float4*)p; }
__device__ __forceinline__ float4 ld4(const bfu* p){
  ushort4 u = *(const ushort4*)p;
  return make_float4(b2f(u.x), b2f(u.y), b2f(u.z), b2f(u.w));
}
__device__ __forceinline__ void stage8(const float* src, bfu* dst){
  float4 f0 = *(const float4*)(src), f1 = *(const float4*)(src+4);
  ushort4 a; a.x=f2b(f0.x); a.y=f2b(f0.y); a.z=f2b(f0.z); a.w=f2b(f0.w);
  ushort4 b; b.x=f2b(f1.x); b.y=f2b(f1.y); b.z=f2b(f1.z); b.w=f2b(f1.w);
  *(ushort4*)dst = a; *(ushort4*)(dst+4) = b;
}
__device__ __forceinline__ void stel(float* p, float v){ *p = v; }
__device__ __forceinline__ void stel(bfu* p, float v){ *p = f2b(v); }

// async global->LDS, 16B per lane; LDS dest = wave-uniform base + lane*16
__device__ __forceinline__ void gload16(const bfu* g, bfu* l){
  __builtin_amdgcn_global_load_lds(
      (const __attribute__((address_space(1))) unsigned int*)(const void*)g,
      (__attribute__((address_space(3))) unsigned int*)(void*)l, 16, 0, 0);
}

// XOR swizzle: element offset of 8-elem chunk `sg` in row `r` (16B granules)
#define SWZ(r, sg) ((((sg) ^ ((r)&7)) << 3))
// element offset of scalar col c in row r under the same swizzle
#define SWZE(r, c) (SWZ(r, (c)>>3) + ((c)&7))

// ================= MFMA GEMM: C[m,n] = sum_k A[m,k]*Bw[n,k] (+bias) =================
// A,Bw bf16 row-major with row stride K (K multiple of 64).
// LDS: linear dest via global_load_lds, source pre-swizzled, reads SWZ'd.
// XCD-swizzled flat block id (requires gridDim.x*gridDim.y % 8 == 0).
template<bool BIAS, class TC0, class TC1>
__global__ __launch_bounds__(256) void gemm_mfma(
    const bfu* __restrict__ A, const bfu* __restrict__ Bw,
    const float* __restrict__ bias,
    TC0* __restrict__ C0, TC1* __restrict__ C1,
    int K, int splitN, int ldc0, int ldc1,
    long sA, long sB, long sC)
{
  __shared__ alignas(16) bfu As[128][64];
  __shared__ alignas(16) bfu Bs[64][64];
  const int tid = threadIdx.x;
  const int gx = gridDim.x;
  int flat = blockIdx.y*gx + blockIdx.x;
  const int cpx = (gx*gridDim.y) >> 3;
  flat = (flat & 7)*cpx + (flat >> 3);          // bijective XCD swizzle
  const int n0 = (flat % gx)*64, m0 = (flat / gx)*128, zb = blockIdx.z;
  A  += (long)zb*sA;
  Bw += (long)zb*sB;
  const int wave = tid>>6, lane = tid&63;
  const int wr = wave>>1, wc = wave&1;
  const int lr = lane&15, lk = lane>>4;
  f32x4 acc[4][2];
  #pragma unroll
  for (int mr=0;mr<4;++mr)
    #pragma unroll
    for (int nr=0;nr<2;++nr){ acc[mr][nr][0]=0.f; acc[mr][nr][1]=0.f; acc[mr][nr][2]=0.f; acc[mr][nr][3]=0.f; }
  for (int k0 = 0; k0 < K; k0 += 64) {
    // A tile: 128 rows x 64 cols = 1024 16B-chunks; linear LDS, swizzled source
    #pragma unroll
    for (int i = 0; i < 4; ++i) {
      int seg = i*256 + tid;
      int r = seg>>3, t = seg&7;
      gload16(A + (long)(m0+r)*K + k0 + ((t ^ (r&7))<<3), &As[0][0] + seg*8);
    }
    #pragma unroll
    for (int i = 0; i < 2; ++i) {
      int seg = i*256 + tid;
      int r = seg>>3, t = seg&7;
      gload16(Bw + (long)(n0+r)*K + k0 + ((t ^ (r&7))<<3), &Bs[0][0] + seg*8);
    }
    __syncthreads();   // compiler drains vmcnt before barrier
    #pragma unroll
    for (int ks = 0; ks < 2; ++ks) {
      bf16x8 af[4], bfr[2];
      #pragma unroll
      for (int mr=0; mr<4; ++mr){ int r = wr*64+mr*16+lr; af[mr]  = *(const bf16x8*)&As[r][SWZ(r, ks*4+lk)]; }
      #pragma unroll
      for (int nr=0; nr<2; ++nr){ int r = wc*32+nr*16+lr; bfr[nr] = *(const bf16x8*)&Bs[r][SWZ(r, ks*4+lk)]; }
      #pragma unroll
      for (int mr=0; mr<4; ++mr)
        #pragma unroll
        for (int nr=0; nr<2; ++nr)
          acc[mr][nr] = __builtin_amdgcn_mfma_f32_16x16x32_bf16(af[mr], bfr[nr], acc[mr][nr], 0,0,0);
    }
    __syncthreads();
  }
  #pragma unroll
  for (int mr=0; mr<4; ++mr) {
    #pragma unroll
    for (int nr=0; nr<2; ++nr) {
      const int col = n0 + wc*32 + nr*16 + lr;
      const float badd = BIAS ? bias[col] : 0.f;
      #pragma unroll
      for (int i=0;i<4;++i) {
        const int row = m0 + wr*64 + mr*16 + lk*4 + i;
        const float v = acc[mr][nr][i] + badd;
        if (col < splitN) stel(C0 + (long)zb*sC + (long)row*ldc0 + col, v);
        else              stel(C1 + (long)row*ldc1 + (col - splitN), v);
      }
    }
  }
}

// ================= u -> bf16 =================
__global__ __launch_bounds__(256) void conv_u(
    const float* __restrict__ u, bfu* __restrict__ ub)
{
  int i = blockIdx.x*256 + threadIdx.x;    // M_*DM/8 = 1769472 segs
  if (i >= M_*DM/8) return;
  stage8(u + (size_t)i*8, ub + (size_t)i*8);
}

// ================= weight prep =================
__global__ __launch_bounds__(256) void prep_w(
    const float* __restrict__ W_in, const float* __restrict__ pw_w,
    const float* __restrict__ W_out,
    bfu* __restrict__ Wt_in, bfu* __restrict__ pw_bf, bfu* __restrict__ Wt_out)
{
  int i = blockIdx.x*256 + threadIdx.x;
  const int n1 = 832*192, n2 = n1 + 384*384, n3 = n2 + 192*384;
  if (i < n1)      { int n=i/192, k=i%192; Wt_in[i]  = f2b(W_in[k*832+n]); }
  else if (i < n2) { int j=i-n1;           pw_bf[j]  = f2b(pw_w[j]); }
  else if (i < n3) { int j=i-n2; int n=j/384, k=j%384; Wt_out[j] = f2b(W_out[k*192+n]); }
}

// ================= depthwise 3x3 + silu =================
__global__ __launch_bounds__(256) void conv3x3_t(
    const bfu* __restrict__ xB, const float* __restrict__ cw,
    const float* __restrict__ cb, bfu* __restrict__ out)
{
  const int tile = blockIdx.x, c0 = blockIdx.y*8, b = blockIdx.z;
  const int h0 = (tile/6)*16, w0 = (tile%6)*16;
  __shared__ alignas(16) bfu tl[18][18][8];
  __shared__ float wl[8][9];
  const int tid = threadIdx.x;
  if (tid < 72) wl[tid/9][tid%9] = cw[(c0 + tid/9)*9 + tid%9];
  for (int i = tid; i < 324; i += 256) {
    int y = i/18, x = i%18;
    int gh = h0+y-1, gw = w0+x-1;
    uint4 v = make_uint4(0,0,0,0);
    if ((unsigned)gh < 96u && (unsigned)gw < 96u)
      v = *(const uint4*)(xB + ((long)(b*L_ + gh*96+gw))*CD + c0);
    *(uint4*)&tl[y][x][0] = v;
  }
  __syncthreads();
  const int px = tid & 15, py = tid >> 4;
  float a[8];
  #pragma unroll
  for (int j=0;j<8;++j) a[j] = cb[c0+j];
  #pragma unroll
  for (int dh=0; dh<3; ++dh)
    #pragma unroll
    for (int dw=0; dw<3; ++dw) {
      uint4 r = *(const uint4*)&tl[py+dh][px+dw][0];
      int t = dh*3+dw;
      a[0] += __uint_as_float(r.x<<16)        * wl[0][t];
      a[1] += __uint_as_float(r.x&0xffff0000u)* wl[1][t];
      a[2] += __uint_as_float(r.y<<16)        * wl[2][t];
      a[3] += __uint_as_float(r.y&0xffff0000u)* wl[3][t];
      a[4] += __uint_as_float(r.z<<16)        * wl[4][t];
      a[5] += __uint_as_float(r.z&0xffff0000u)* wl[5][t];
      a[6] += __uint_as_float(r.w<<16)        * wl[6][t];
      a[7] += __uint_as_float(r.w&0xffff0000u)* wl[7][t];
    }
  #pragma unroll
  for (int j=0;j<8;++j) a[j] = a[j]*sigm(a[j]);
  uint4 o;
  o.x = (unsigned)f2b(a[0]) | ((unsigned)f2b(a[1])<<16);
  o.y = (unsigned)f2b(a[2]) | ((unsigned)f2b(a[3])<<16);
  o.z = (unsigned)f2b(a[4]) | ((unsigned)f2b(a[5])<<16);
  o.w = (unsigned)f2b(a[6]) | ((unsigned)f2b(a[7])<<16);
  *(uint4*)(out + ((long)(b*L_ + (h0+py)*96 + (w0+px)))*CD + c0) = o;
}

// ================= depthwise 5x5 =================
__global__ __launch_bounds__(256) void conv5x5_t(
    const bfu* __restrict__ xin, const float* __restrict__ cw,
    const float* __restrict__ cb, bfu* __restrict__ out)
{
  const int tile = blockIdx.x, c0 = blockIdx.y*8, b = blockIdx.z;
  const int h0 = (tile/6)*16, w0 = (tile%6)*16;
  __shared__ alignas(16) bfu tl[20][20][8];
  __shared__ float wl[8][25];
  const int tid = threadIdx.x;
  if (tid < 200) wl[tid/25][tid%25] = cw[(c0 + tid/25)*25 + tid%25];
  for (int i = tid; i < 400; i += 256) {
    int y = i/20, x = i%20;
    int gh = h0+y-2, gw = w0+x-2;
    uint4 v = make_uint4(0,0,0,0);
    if ((unsigned)gh < 96u && (unsigned)gw < 96u)
      v = *(const uint4*)(xin + ((long)(b*L_ + gh*96+gw))*CD + c0);
    *(uint4*)&tl[y][x][0] = v;
  }
  __syncthreads();
  const int px = tid & 15, py = tid >> 4;
  float a[8];
  #pragma unroll
  for (int j=0;j<8;++j) a[j] = cb[c0+j];
  #pragma unroll
  for (int dh=0; dh<5; ++dh)
    #pragma unroll
    for (int dw=0; dw<5; ++dw) {
      uint4 r = *(const uint4*)&tl[py+dh][px+dw][0];
      int t = dh*5+dw;
      a[0] += __uint_as_float(r.x<<16)        * wl[0][t];
      a[1] += __uint_as_float(r.x&0xffff0000u)* wl[1][t];
      a[2] += __uint_as_float(r.y<<16)        * wl[2][t];
      a[3] += __uint_as_float(r.y&0xffff0000u)* wl[3][t];
      a[4] += __uint_as_float(r.z<<16)        * wl[4][t];
      a[5] += __uint_as_float(r.z&0xffff0000u)* wl[5][t];
      a[6] += __uint_as_float(r.w<<16)        * wl[6][t];
      a[7] += __uint_as_float(r.w&0xffff0000u)* wl[7][t];
    }
  uint4 o;
  o.x = (unsigned)f2b(a[0]) | ((unsigned)f2b(a[1])<<16);
  o.y = (unsigned)f2b(a[2]) | ((unsigned)f2b(a[3])<<16);
  o.z = (unsigned)f2b(a[4]) | ((unsigned)f2b(a[5])<<16);
  o.w = (unsigned)f2b(a[6]) | ((unsigned)f2b(a[7])<<16);
  *(uint4*)(out + ((long)(b*L_ + (h0+py)*96 + (w0+px)))*DI + c0) = o;
}

// ================= K_soft =================
__global__ __launch_bounds__(256) void ksoft_kernel(
    const bfu* __restrict__ xB2, bfu* __restrict__ Ksoft)
{
  int p = blockIdx.x * 4 + (threadIdx.x >> 6);
  int lane = threadIdx.x & 63;
  float v = b2f(xB2[(long)p * CD + DI + lane]);
  float k = sigm(v);
  float s = k;
  #pragma unroll
  for (int o = 32; o; o >>= 1) s += __shfl_xor(s, o);
  Ksoft[((long)p << 6) + lane] = f2b(k / (s + 1e-6f));
}

// ================= proto partials (MFMA): proto[s][d] += K[l][s]*V[l][d] =================
__global__ __launch_bounds__(256) void proto_mfma(
    const bfu* __restrict__ Ksf, const bfu* __restrict__ Vs, float* __restrict__ part)
{
  const int ch = blockIdx.x, bh = blockIdx.y;
  const int b = bh / NH, hh = bh % NH;
  __shared__ alignas(16) bfu Kst[64][72];   // K^T [s][l], swizzled
  __shared__ alignas(16) bfu Vtt[64][72];   // V^T [d][l], swizzled
  const int tid = threadIdx.x;
  const int wave = tid>>6, lane = tid&63;
  const int wr = wave>>1, wc = wave&1;
  const int lr = lane&15, lk = lane>>4;
  f32x4 acc[2][2];
  #pragma unroll
  for (int mr=0;mr<2;++mr)
    #pragma unroll
    for (int nr=0;nr<2;++nr){ acc[mr][nr][0]=0.f; acc[mr][nr][1]=0.f; acc[mr][nr][2]=0.f; acc[mr][nr][3]=0.f; }
  const int lbeg = ch * (L_/LSPLIT);
  for (int l0 = lbeg; l0 < lbeg + L_/LSPLIT; l0 += 64) {
    __syncthreads();
    #pragma unroll
    for (int i=0;i<2;++i) {
      const int li = tid&63, sg = (tid>>6) + i*4;
      const long lrow = (long)b*L_ + l0 + li;
      u16x8 kv = *(const u16x8*)(Ksf + (lrow<<6) + sg*8);
      u16x8 vv = *(const u16x8*)(Vs + lrow*DI + hh*HD + sg*8);
      #pragma unroll
      for (int j=0;j<8;++j) {
        int r = sg*8+j;
        Kst[r][SWZE(r, li)] = kv[j];
        Vtt[r][SWZE(r, li)] = vv[j];
      }
    }
    __syncthreads();
    #pragma unroll
    for (int ks=0; ks<2; ++ks) {
      bf16x8 af[2], bfr[2];
      #pragma unroll
      for (int mr=0;mr<2;++mr){ int r = wr*32+mr*16+lr; af[mr]  = *(const bf16x8*)&Kst[r][SWZ(r, ks*4+lk)]; }
      #pragma unroll
      for (int nr=0;nr<2;++nr){ int r = wc*32+nr*16+lr; bfr[nr] = *(const bf16x8*)&Vtt[r][SWZ(r, ks*4+lk)]; }
      #pragma unroll
      for (int mr=0;mr<2;++mr)
        #pragma unroll
        for (int nr=0;nr<2;++nr)
          acc[mr][nr] = __builtin_amdgcn_mfma_f32_16x16x32_bf16(af[mr], bfr[nr], acc[mr][nr], 0,0,0);
    }
  }
  float* dst = part + ((long)bh*LSPLIT + ch) * 4096;
  #pragma unroll
  for (int mr=0;mr<2;++mr)
    #pragma unroll
    for (int nr=0;nr<2;++nr)
      #pragma unroll
      for (int i=0;i<4;++i) {
        int row = wr*32+mr*16+lk*4+i, col = wc*32+nr*16+lr;
        dst[row*64+col] = acc[mr][nr][i];
      }
}

// ================= reduce proto chunks -> bf16 =================
__global__ __launch_bounds__(256) void reduce_proto(
    const float* __restrict__ part, bfu* __restrict__ proto)
{
  int idx = blockIdx.x * 256 + threadIdx.x;
  int bh = idx >> 12, sd = idx & 4095;
  const float* p = part + ((long)bh*LSPLIT)*4096 + sd;
  float s = 0.f;
  #pragma unroll
  for (int c = 0; c < LSPLIT; ++c) s += p[c*4096];
  proto[idx] = f2b(s);
}

// ================= flash PV (MFMA): S=proto@V^T, P=exp(S*scale), pacc+=P@V =================
__global__ __launch_bounds__(256) void flashpv_mfma(
    const bfu* __restrict__ proto, const bfu* __restrict__ Vs,
    float* __restrict__ pacc_part, float* __restrict__ dsum_part)
{
  const int ch = blockIdx.x, bh = blockIdx.y;
  const int b = bh / NH, hh = bh % NH;
  __shared__ alignas(16) bfu Pt[64][72];    // proto [s][d], swizzled
  __shared__ alignas(16) bfu Vt[64][72];    // V [l][d], swizzled
  __shared__ alignas(16) bfu Vtt[64][72];   // V^T [d][l], swizzled
  __shared__ alignas(16) bfu Ptl[64][72];   // P [s][l], swizzled
  __shared__ float dsh[2][64];
  const int tid = threadIdx.x;
  const int wave = tid>>6, lane = tid&63;
  const int wr = wave>>1, wc = wave&1;
  const int lr = lane&15, lk = lane>>4;
  {
    const bfu* src = proto + ((long)bh<<12);
    #pragma unroll
    for (int i=0;i<2;++i) {
      const int li = tid&63, sg = (tid>>6) + i*4;
      *(uint4*)&Pt[li][SWZ(li, sg)] = *(const uint4*)(src + li*64 + sg*8);
    }
  }
  f32x4 pacc[2][2];
  #pragma unroll
  for (int mr=0;mr<2;++mr)
    #pragma unroll
    for (int nr=0;nr<2;++nr){ pacc[mr][nr][0]=0.f; pacc[mr][nr][1]=0.f; pacc[mr][nr][2]=0.f; pacc[mr][nr][3]=0.f; }
  float ds[8] = {};
  const int lbeg = ch * (L_/LSPLIT);
  for (int l0 = lbeg; l0 < lbeg + L_/LSPLIT; l0 += 64) {
    __syncthreads();
    #pragma unroll
    for (int i=0;i<2;++i) {
      const int li = tid&63, sg = (tid>>6) + i*4;
      u16x8 vv = *(const u16x8*)(Vs + ((long)b*L_ + l0 + li)*DI + hh*HD + sg*8);
      *(u16x8*)&Vt[li][SWZ(li, sg)] = vv;
      #pragma unroll
      for (int j=0;j<8;++j) { int r = sg*8+j; Vtt[r][SWZE(r, li)] = vv[j]; }
    }
    __syncthreads();
    f32x4 sacc[2][2];
    #pragma unroll
    for (int mr=0;mr<2;++mr)
      #pragma unroll
      for (int nr=0;nr<2;++nr){ sacc[mr][nr][0]=0.f; sacc[mr][nr][1]=0.f; sacc[mr][nr][2]=0.f; sacc[mr][nr][3]=0.f; }
    #pragma unroll
    for (int ks=0; ks<2; ++ks) {
      bf16x8 af[2], bfr[2];
      #pragma unroll
      for (int mr=0;mr<2;++mr){ int r = wr*32+mr*16+lr; af[mr]  = *(const bf16x8*)&Pt[r][SWZ(r, ks*4+lk)]; }
      #pragma unroll
      for (int nr=0;nr<2;++nr){ int r = wc*32+nr*16+lr; bfr[nr] = *(const bf16x8*)&Vt[r][SWZ(r, ks*4+lk)]; }
      #pragma unroll
      for (int mr=0;mr<2;++mr)
        #pragma unroll
        for (int nr=0;nr<2;++nr)
          sacc[mr][nr] = __builtin_amdgcn_mfma_f32_16x16x32_bf16(af[mr], bfr[nr], sacc[mr][nr], 0,0,0);
    }
    #pragma unroll
    for (int mr=0;mr<2;++mr)
      #pragma unroll
      for (int nr=0;nr<2;++nr)
        #pragma unroll
        for (int i=0;i<4;++i) {
          int row = wr*32+mr*16+lk*4+i, col = wc*32+nr*16+lr;
          float p = __expf(sacc[mr][nr][i]*SCALE_);
          ds[mr*4+i] += p;
          Ptl[row][SWZE(row, col)] = f2b(p);
        }
    __syncthreads();
    #pragma unroll
    for (int ks=0; ks<2; ++ks) {
      bf16x8 af2[2], bf2[2];
      #pragma unroll
      for (int mr=0;mr<2;++mr){ int r = wr*32+mr*16+lr; af2[mr] = *(const bf16x8*)&Ptl[r][SWZ(r, ks*4+lk)]; }
      #pragma unroll
      for (int nr=0;nr<2;++nr){ int r = wc*32+nr*16+lr; bf2[nr] = *(const bf16x8*)&Vtt[r][SWZ(r, ks*4+lk)]; }
      #pragma unroll
      for (int mr=0;mr<2;++mr)
        #pragma unroll
        for (int nr=0;nr<2;++nr)
          pacc[mr][nr] = __builtin_amdgcn_mfma_f32_16x16x32_bf16(af2[mr], bf2[nr], pacc[mr][nr], 0,0,0);
    }
  }
  float* dst = pacc_part + ((long)bh*LSPLIT + ch) * 4096;
  #pragma unroll
  for (int mr=0;mr<2;++mr)
    #pragma unroll
    for (int nr=0;nr<2;++nr)
      #pragma unroll
      for (int i=0;i<4;++i) {
        int row = wr*32+mr*16+lk*4+i, col = wc*32+nr*16+lr;
        dst[row*64+col] = pacc[mr][nr][i];
      }
  #pragma unroll
  for (int o=1;o<16;o<<=1)
    #pragma unroll
    for (int j=0;j<8;++j) ds[j] += __shfl_xor(ds[j], o);
  if (lr == 0) {
    #pragma unroll
    for (int mr=0;mr<2;++mr)
      #pragma unroll
      for (int i=0;i<4;++i)
        dsh[wc][wr*32+mr*16+lk*4+i] = ds[mr*4+i];
  }
  __syncthreads();
  if (tid < 64)
    dsum_part[((long)bh*LSPLIT + ch)*64 + tid] = dsh[0][tid] + dsh[1][tid];
}

// ================= reduce flash partials -> R2t [b][n=hh*64+d][k=s] bf16 =================
__global__ __launch_bounds__(256) void reduce_R2(
    const float* __restrict__ pacc_part, const float* __restrict__ dsum_part,
    bfu* __restrict__ R2t)
{
  int idx = blockIdx.x * 256 + threadIdx.x;   // 48*4096
  int bh = idx >> 12, s = (idx >> 6) & 63, d = idx & 63;
  int b = bh / NH, hh = bh % NH;
  float pa = 0.f, dsv = 0.f;
  #pragma unroll
  for (int c = 0; c < LSPLIT; ++c) {
    pa += pacc_part[((long)bh*LSPLIT + c)*4096 + (s<<6) + d];
    dsv += dsum_part[((long)bh*LSPLIT + c)*64 + s];
  }
  R2t[(((long)b*DI) + hh*HD + d)*64 + s] = f2b(pa / dsv);
}

// ================= y = fine + V*D ; LN ; *z =================
__global__ __launch_bounds__(128) void ln_kernel(
    const bfu* __restrict__ fine, const bfu* __restrict__ xB2,
    const bfu* __restrict__ z, const float* __restrict__ Dv,
    const float* __restrict__ ln_g, const float* __restrict__ ln_b,
    bfu* __restrict__ yn)
{
  const int p = blockIdx.x;
  const int tid = threadIdx.x;
  __shared__ float sh[2], sh2[2];
  float y[3]; float s = 0.f, ss = 0.f;
  #pragma unroll
  for (int k = 0; k < 3; ++k) {
    int c = tid + (k << 7);
    float f = b2f(fine[(long)p*DI + c]) + b2f(xB2[(long)p*CD + c]) * Dv[c >> 6];
    y[k] = f; s += f; ss += f*f;
  }
  #pragma unroll
  for (int o = 32; o; o >>= 1) { s += __shfl_xor(s, o); ss += __shfl_xor(ss, o); }
  if ((tid & 63) == 0) { sh[tid >> 6] = s; sh2[tid >> 6] = ss; }
  __syncthreads();
  s = sh[0] + sh[1]; ss = sh2[0] + sh2[1];
  float mu = s * (1.f/384.f);
  float var = ss * (1.f/384.f) - mu*mu;
  float rs = rsqrtf(var + 1e-5f);
  #pragma unroll
  for (int k = 0; k < 3; ++k) {
    int c = tid + (k << 7);
    float o2 = (y[k] - mu) * rs * ln_g[c] + ln_b[c];
    yn[(long)p*DI + c] = f2b(o2 * b2f(z[(long)p*DI + c]));
  }
}

extern "C" void kernel_launch(void* const* d_in, const int* in_sizes, int n_in,
                              void* d_out, int out_size, void* d_ws, size_t ws_size,
                              hipStream_t stream) {
  const float* u      = (const float*)d_in[0];
  const float* W_in   = (const float*)d_in[1];
  const float* conv_w = (const float*)d_in[2];
  const float* conv_b = (const float*)d_in[3];
  const float* dw_w   = (const float*)d_in[4];
  const float* dw_b   = (const float*)d_in[5];
  const float* pw_w   = (const float*)d_in[6];
  const float* pw_b   = (const float*)d_in[7];
  const float* Dv     = (const float*)d_in[8];
  const float* ln_g   = (const float*)d_in[9];
  const float* ln_b   = (const float*)d_in[10];
  const float* W_out  = (const float*)d_in[11];
  float* out = (float*)d_out;

  bfu* z_bf = (bfu*)d_out;      // M_*384 bf16 == out_size*4 bytes, dead before final write

  char* ws = (char*)d_ws;
  size_t off = 0;
  bfu* xB_bf   = (bfu*)(ws + off); off += (size_t)M_*CD*2;   // gemm1 cols 384..; later fine
  bfu* xB2_bf  = (bfu*)(ws + off); off += (size_t)M_*CD*2;   // conv3 out, live to LN
  bfu* xloc_bf = (bfu*)(ws + off); off += (size_t)M_*DI*2;   // u_bf (step 0-1), conv5 out (3-4),
                                                             // part/dsum (5-6), yn (8-9)
  bfu* Vs_bf   = (bfu*)(ws + off); off += (size_t)M_*DI*2;
  bfu* Ksf_bf  = (bfu*)(ws + off); off += (size_t)M_*DS*2;
  bfu* Wt_in   = (bfu*)(ws + off); off += (size_t)832*192*2;
  bfu* pw_bf   = (bfu*)(ws + off); off += (size_t)384*384*2;
  bfu* Wt_out  = (bfu*)(ws + off); off += (size_t)192*384*2;
  bfu* R2t     = (bfu*)(ws + off); off += (size_t)8*DI*64*2;
  bfu* proto_b = (bfu*)(ws + off); off += (size_t)48*4096*2;
  // static total ~256.4 MB. Overlays in the xloc region (56.6 MB):
  bfu*   u_bf  = xloc_bf;                               // 28.3 MB, live step 0->1
  float* part  = (float*)xloc_bf;                       // 48*LSPLIT*4096 f32, live 5->6
  float* dsum  = part + (size_t)48*LSPLIT*4096;         // 48*LSPLIT*64 f32

  bfu* fine_bf = xB_bf;
  bfu* yn_bf   = xloc_bf;

  // 0) prep: weights transpose+convert, u -> bf16
  prep_w<<<1488, 256, 0, stream>>>(W_in, pw_w, W_out, Wt_in, pw_bf, Wt_out);
  conv_u<<<(M_*DM/8 + 255)/256, 256, 0, stream>>>(u, u_bf);
  // 1) zxB = u @ W_in
  gemm_mfma<false,bfu,bfu><<<dim3(13,576,1), 256, 0, stream>>>(
      u_bf, Wt_in, nullptr, z_bf, xB_bf, 192, 384, 384, 448, 0, 0, 0);
  // 2) depthwise 3x3 + silu
  conv3x3_t<<<dim3(36,56,8), 256, 0, stream>>>(xB_bf, conv_w, conv_b, xB2_bf);
  // 2b) K_soft
  ksoft_kernel<<<M_/4, 256, 0, stream>>>(xB2_bf, Ksf_bf);
  // 3) depthwise 5x5 (overwrites u_bf region — u_bf dead after step 1)
  conv5x5_t<<<dim3(36,48,8), 256, 0, stream>>>(xB2_bf, dw_w, dw_b, xloc_bf);
  // 4) pointwise: Vs = xloc @ pw_w^T + pw_b  (last reader of xloc)
  gemm_mfma<true,bfu,bfu><<<dim3(6,576,1), 256, 0, stream>>>(
      xloc_bf, pw_bf, pw_b, Vs_bf, (bfu*)nullptr, 384, 1<<30, 384, 0, 0, 0, 0);
  // 5) proto (MFMA partials + reduce) — part overlays xloc region
  proto_mfma<<<dim3(LSPLIT,48), 256, 0, stream>>>(Ksf_bf, Vs_bf, part);
  reduce_proto<<<768, 256, 0, stream>>>(part, proto_b);
  // 6) flash attention (MFMA) partials + reduce -> R2t
  flashpv_mfma<<<dim3(LSPLIT,48), 256, 0, stream>>>(proto_b, Vs_bf, part, dsum);
  reduce_R2<<<768, 256, 0, stream>>>(part, dsum, R2t);
  // 7) fine = Ksoft @ refined^T
  gemm_mfma<false,bfu,bfu><<<dim3(6,72,8), 256, 0, stream>>>(
      Ksf_bf, R2t, nullptr, fine_bf, (bfu*)nullptr, 64, 1<<30, 384, 0,
      (long)L_*64, (long)DI*64, (long)L_*384);
  // 8) y = fine + V*D ; LN ; *z  (yn overwrites xloc region)
  ln_kernel<<<M_, 128, 0, stream>>>(fine_bf, xB2_bf, z_bf, Dv, ln_g, ln_b, yn_bf);
  // 9) out = yn @ W_out
  gemm_mfma<false,float,float><<<dim3(3,576,1), 256, 0, stream>>>(
      yn_bf, Wt_out, nullptr, out, (float*)nullptr, 384, 1<<30, 192, 0, 0, 0, 0);
}